// Round 1
// baseline (10989.992 us; speedup 1.0000x reference)
//
#include <hip/hip_runtime.h>
#include <hip/hip_bf16.h>
#include <cmath>

// ---------------------------------------------------------------------------
// Sizes (fixed by the problem)
// ---------------------------------------------------------------------------
// x:  (8,256,5,5,4,4,3) -> x2 (2048, 1200) fp32
// D:  (1200, 2400) fp32, row-major
// out: (2048, 1200) fp32
// ITER_EIGENVAL = 20, ITER_FISTA = 16, COUPLE_STRENGTH = 0.1

#define DS 1200
#define DD 2400
#define BNROWS 2048

// ---------------------------------------------------------------------------
// JAX threefry2x32 + XLA f32 erfinv (to reproduce jax.random.normal(key(42)))
// ---------------------------------------------------------------------------
__device__ __forceinline__ unsigned rotl32(unsigned x, int d) {
    return (x << d) | (x >> (32 - d));
}

__device__ void threefry2x32(unsigned k0, unsigned k1, unsigned x0, unsigned x1,
                             unsigned* o0, unsigned* o1) {
    unsigned ks0 = k0, ks1 = k1, ks2 = k0 ^ k1 ^ 0x1BD11BDAu;
    const int rotA[4] = {13, 15, 26, 6};
    const int rotB[4] = {17, 29, 16, 24};
    x0 += ks0; x1 += ks1;
    #pragma unroll
    for (int r = 0; r < 4; r++) { x0 += x1; x1 = rotl32(x1, rotA[r]); x1 ^= x0; }
    x0 += ks1; x1 += ks2 + 1u;
    #pragma unroll
    for (int r = 0; r < 4; r++) { x0 += x1; x1 = rotl32(x1, rotB[r]); x1 ^= x0; }
    x0 += ks2; x1 += ks0 + 2u;
    #pragma unroll
    for (int r = 0; r < 4; r++) { x0 += x1; x1 = rotl32(x1, rotA[r]); x1 ^= x0; }
    x0 += ks0; x1 += ks1 + 3u;
    #pragma unroll
    for (int r = 0; r < 4; r++) { x0 += x1; x1 = rotl32(x1, rotB[r]); x1 ^= x0; }
    x0 += ks1; x1 += ks2 + 4u;
    #pragma unroll
    for (int r = 0; r < 4; r++) { x0 += x1; x1 = rotl32(x1, rotA[r]); x1 ^= x0; }
    x0 += ks2; x1 += ks0 + 5u;
    *o0 = x0; *o1 = x1;
}

__device__ float erfinv_f32(float x) {
    // XLA f32 ErfInv (Giles 2012 polynomial)
    float w = -logf((1.0f - x) * (1.0f + x));
    float p;
    if (w < 5.0f) {
        w -= 2.5f;
        p = 2.81022636e-08f;
        p = fmaf(p, w, 3.43273939e-07f);
        p = fmaf(p, w, -3.5233877e-06f);
        p = fmaf(p, w, -4.39150654e-06f);
        p = fmaf(p, w, 0.00021858087f);
        p = fmaf(p, w, -0.00125372503f);
        p = fmaf(p, w, -0.00417768164f);
        p = fmaf(p, w, 0.246640727f);
        p = fmaf(p, w, 1.50140941f);
    } else {
        w = sqrtf(w) - 3.0f;
        p = -0.000200214257f;
        p = fmaf(p, w, 0.000100950558f);
        p = fmaf(p, w, 0.00134934322f);
        p = fmaf(p, w, -0.00367342844f);
        p = fmaf(p, w, 0.00573950773f);
        p = fmaf(p, w, -0.0076224613f);
        p = fmaf(p, w, 0.00943887047f);
        p = fmaf(p, w, 1.00167406f);
        p = fmaf(p, w, 2.83297682f);
    }
    return p * x;
}

__device__ float bits_to_normal(unsigned bits) {
    // jax uniform in [lo, hi): bits>>9 | exp(1.0), bitcast, -1 -> [0,1)
    unsigned fb = (bits >> 9) | 0x3F800000u;
    float u01 = __uint_as_float(fb) - 1.0f;
    const float lo = -0.99999994f;            // nextafter(-1, 0) in f32
    float u = u01 * 2.0f + lo;                // (hi - lo) rounds to 2.0f in f32
    u = fmaxf(lo, u);
    return 1.41421356237f * erfinv_f32(u);    // sqrt(2) * erfinv(u)
}

// ---------------------------------------------------------------------------
// Power iteration kernels (deterministic: fixed-slot partial sums, no atomics)
// ---------------------------------------------------------------------------
// ws layout (floats):
//   wbuf[2400] : current (unnormalized) 2400-vector w
//   u[1200]    : D @ v
//   part[21*10]: per-iteration block partials of ||w||^2 (slot-fixed)
//   scal[3]    : L, 1/L, thr = 0.1/L

__global__ void k_init(float* __restrict__ wbuf, float* __restrict__ part) {
    int tid = threadIdx.x;  // 256 threads, 1 block
    for (int i = tid; i < 21 * 10; i += 256) part[i] = 0.0f;
    __shared__ float red[256];
    float local2 = 0.0f;
    for (int p = tid; p < DS; p += 256) {
        unsigned r0, r1;
        threefry2x32(0u, 42u, (unsigned)p, (unsigned)(DS + p), &r0, &r1);
        float n0 = bits_to_normal(r0);
        float n1 = bits_to_normal(r1);
        wbuf[p] = n0;
        wbuf[DS + p] = n1;
        local2 += n0 * n0 + n1 * n1;
    }
    red[tid] = local2;
    __syncthreads();
    for (int s = 128; s > 0; s >>= 1) {
        if (tid < s) red[tid] += red[tid + s];
        __syncthreads();
    }
    if (tid == 0) part[0] = red[0];
}

// u[row] = (sum_k D[row][k] * w[k]) * rsqrt(sum(part))    (i.e. u = D @ (w/||w||))
__global__ __launch_bounds__(256) void k_mv_rows(const float* __restrict__ D,
                                                 const float* __restrict__ w,
                                                 const float* __restrict__ part,
                                                 float* __restrict__ u) {
    float s2 = 0.0f;
    #pragma unroll
    for (int i = 0; i < 10; i++) s2 += part[i];
    float rn = 1.0f / sqrtf(s2);
    int wave = threadIdx.x >> 6;
    int lane = threadIdx.x & 63;
    int row = blockIdx.x * 4 + wave;  // grid 300 -> rows 0..1199
    const float4* Dr = (const float4*)(D + (size_t)row * DD);
    const float4* w4p = (const float4*)w;
    float acc = 0.0f;
    #pragma unroll
    for (int i = 0; i < 10; i++) {
        int c4 = lane + i * 64;       // 600 float4 per row
        if (c4 < 600) {
            float4 d4 = Dr[c4];
            float4 w4 = w4p[c4];
            acc += d4.x * w4.x + d4.y * w4.y + d4.z * w4.z + d4.w * w4.w;
        }
    }
    #pragma unroll
    for (int off = 32; off > 0; off >>= 1) acc += __shfl_xor(acc, off, 64);
    if (lane == 0) u[row] = acc * rn;
}

// w[k] = sum_d D[d][k] * u[d]; part_out[block] = block partial of ||w||^2
__global__ __launch_bounds__(256) void k_mv_cols(const float* __restrict__ D,
                                                 const float* __restrict__ u,
                                                 float* __restrict__ w,
                                                 float* __restrict__ part_out) {
    __shared__ float us[DS];
    __shared__ float red[256];
    int tid = threadIdx.x;
    for (int i = tid; i < DS; i += 256) us[i] = u[i];
    __syncthreads();
    int k = blockIdx.x * 256 + tid;   // grid 10 -> 2400 cols exactly
    const float* Dk = D + k;
    float acc = 0.0f;
    #pragma unroll 4
    for (int d = 0; d < DS; d++) acc = fmaf(Dk[(size_t)d * DD], us[d], acc);
    w[k] = acc;
    red[tid] = acc * acc;
    __syncthreads();
    for (int s = 128; s > 0; s >>= 1) {
        if (tid < s) red[tid] += red[tid + s];
        __syncthreads();
    }
    if (tid == 0) part_out[blockIdx.x] = red[0];
}

__global__ void k_fin(const float* __restrict__ part20, float* __restrict__ scal) {
    if (threadIdx.x == 0) {
        float s = 0.0f;
        for (int i = 0; i < 10; i++) s += part20[i];
        float L = sqrtf(s);
        scal[0] = L;
        scal[1] = 1.0f / L;
        scal[2] = 0.1f / L;
    }
}

__global__ void k_zero(float4* __restrict__ p, int n4) {
    int i = blockIdx.x * blockDim.x + threadIdx.x;
    if (i < n4) p[i] = float4{0.f, 0.f, 0.f, 0.f};
}

// ---------------------------------------------------------------------------
// fp32 tiled GEMM, fused epilogues.
//   C[m][n] = sum_k A[m][k] * (TRANSB ? B[n][k] : B[k][n])
// EPI 0: C = acc            (final recon -> d_out)
// EPI 1: C = acc - X        (residual r = y@D^T - x2)
// EPI 2: FISTA update: z_new = soft(y - acc/L, thr); y = z_new + mom*(z_new-z)
// ---------------------------------------------------------------------------
template <int BM, int BN, int EPI, bool TRANSB>
__global__ __launch_bounds__(256) void gemm_kernel(
    const float* __restrict__ A, int lda,
    const float* __restrict__ B, int ldb,
    float* __restrict__ C, int ldc,
    const float* __restrict__ X,
    float* __restrict__ Z, float* __restrict__ Y,
    const float* __restrict__ scal, float mom,
    int M, int N, int K) {
    constexpr int BK = 16;
    constexpr int MG = BM / 64;
    constexpr int NG = BN / 64;
    __shared__ float As[BK][BM];
    __shared__ float Bs[BK][BN];
    int tid = threadIdx.x;
    int tx = tid & 15, ty = tid >> 4;
    int m0 = blockIdx.y * BM, n0 = blockIdx.x * BN;

    float acc[MG][NG][4][4];
    #pragma unroll
    for (int g = 0; g < MG; g++)
        #pragma unroll
        for (int h = 0; h < NG; h++)
            #pragma unroll
            for (int i = 0; i < 4; i++)
                #pragma unroll
                for (int j = 0; j < 4; j++) acc[g][h][i][j] = 0.0f;

    float invL = 0.0f, thr = 0.0f;
    if (EPI == 2) { invL = scal[1]; thr = scal[2]; }

    for (int k0 = 0; k0 < K; k0 += BK) {
        // A tile: BM x 16, stored transposed As[kk][m]
        #pragma unroll
        for (int i = 0; i < BM / 64; i++) {
            int f = tid + i * 256;
            int row = f >> 2, kk = (f & 3) << 2;
            float4 av = *(const float4*)(A + (size_t)(m0 + row) * lda + k0 + kk);
            As[kk + 0][row] = av.x;
            As[kk + 1][row] = av.y;
            As[kk + 2][row] = av.z;
            As[kk + 3][row] = av.w;
        }
        // B tile
        if (TRANSB) {
            #pragma unroll
            for (int i = 0; i < BN / 64; i++) {
                int f = tid + i * 256;
                int row = f >> 2, kk = (f & 3) << 2;
                float4 bv = {0.f, 0.f, 0.f, 0.f};
                if (n0 + row < N)
                    bv = *(const float4*)(B + (size_t)(n0 + row) * ldb + k0 + kk);
                Bs[kk + 0][row] = bv.x;
                Bs[kk + 1][row] = bv.y;
                Bs[kk + 2][row] = bv.z;
                Bs[kk + 3][row] = bv.w;
            }
        } else {
            #pragma unroll
            for (int i = 0; i < BN / 64; i++) {
                int f = tid + i * 256;
                int kk = f / (BN / 4), col = (f % (BN / 4)) * 4;
                float4 bv = {0.f, 0.f, 0.f, 0.f};
                if (n0 + col < N)
                    bv = *(const float4*)(B + (size_t)(k0 + kk) * ldb + n0 + col);
                *(float4*)&Bs[kk][col] = bv;
            }
        }
        __syncthreads();
        #pragma unroll
        for (int kk = 0; kk < BK; kk++) {
            float4 a[MG], b[NG];
            #pragma unroll
            for (int g = 0; g < MG; g++) a[g] = *(const float4*)&As[kk][ty * 4 + g * 64];
            #pragma unroll
            for (int h = 0; h < NG; h++) b[h] = *(const float4*)&Bs[kk][tx * 4 + h * 64];
            #pragma unroll
            for (int g = 0; g < MG; g++) {
                const float* ap = (const float*)&a[g];
                #pragma unroll
                for (int h = 0; h < NG; h++) {
                    const float* bp = (const float*)&b[h];
                    #pragma unroll
                    for (int i = 0; i < 4; i++)
                        #pragma unroll
                        for (int j = 0; j < 4; j++)
                            acc[g][h][i][j] = fmaf(ap[i], bp[j], acc[g][h][i][j]);
                }
            }
        }
        __syncthreads();
    }

    // epilogue
    #pragma unroll
    for (int g = 0; g < MG; g++)
        #pragma unroll
        for (int i = 0; i < 4; i++) {
            int m = m0 + ty * 4 + g * 64 + i;
            #pragma unroll
            for (int h = 0; h < NG; h++)
                #pragma unroll
                for (int j = 0; j < 4; j++) {
                    int n = n0 + tx * 4 + h * 64 + j;
                    if (n < N) {
                        size_t idx = (size_t)m * ldc + n;
                        float v = acc[g][h][i][j];
                        if (EPI == 0) {
                            C[idx] = v;
                        } else if (EPI == 1) {
                            C[idx] = v - X[idx];
                        } else {
                            float yv = Y[idx];
                            float zv = Z[idx];
                            float gs = yv - v * invL;
                            float az = fabsf(gs) - thr;
                            float zn = (az > 0.0f) ? copysignf(az, gs) : 0.0f;
                            Y[idx] = zn + mom * (zn - zv);
                            Z[idx] = zn;
                        }
                    }
                }
        }
}

// ---------------------------------------------------------------------------
// Launch
// ---------------------------------------------------------------------------
extern "C" void kernel_launch(void* const* d_in, const int* in_sizes, int n_in,
                              void* d_out, int out_size, void* d_ws, size_t ws_size,
                              hipStream_t stream) {
    const float* x = (const float*)d_in[0];   // (2048, 1200)
    const float* D = (const float*)d_in[1];   // (1200, 2400)
    float* out = (float*)d_out;               // (2048, 1200)
    float* ws = (float*)d_ws;

    float* wbuf = ws;                 // 2400
    float* u    = ws + 2400;          // 1200
    float* part = ws + 3600;          // 210
    float* scal = ws + 3810;          // 3
    float* z    = ws + 4096;          // 2048*2400
    float* y    = z + (size_t)BNROWS * DD;
    float* r    = y + (size_t)BNROWS * DD;  // 2048*1200

    // ---- power iteration: L = ||(D^T D)^20-ish|| per reference semantics ----
    k_init<<<1, 256, 0, stream>>>(wbuf, part);
    for (int j = 0; j < 20; j++) {
        k_mv_rows<<<300, 256, 0, stream>>>(D, wbuf, part + j * 10, u);
        k_mv_cols<<<10, 256, 0, stream>>>(D, u, wbuf, part + (j + 1) * 10);
    }
    k_fin<<<1, 64, 0, stream>>>(part + 200, scal);

    // ---- zero-init z and y (contiguous) ----
    {
        int n4 = 2 * BNROWS * DD / 4;
        int blocks = (n4 + 255) / 256;
        k_zero<<<blocks, 256, 0, stream>>>((float4*)z, n4);
    }

    // ---- FISTA ----
    float t = 1.0f;
    for (int i = 0; i < 16; i++) {
        float tn = 0.5f * (1.0f + sqrtf(1.0f + 4.0f * t * t));
        float mom = (t - 1.0f) / tn;
        t = tn;
        // r = y @ D^T - x2   (2048x1200)
        gemm_kernel<64, 128, 1, true><<<dim3(10, 32), 256, 0, stream>>>(
            y, DD, D, DD, r, DS, x, nullptr, nullptr, nullptr, 0.0f,
            BNROWS, DS, DD);
        // grad = r @ D (2048x2400) fused with soft-threshold + momentum update
        gemm_kernel<128, 128, 2, false><<<dim3(19, 16), 256, 0, stream>>>(
            r, DS, D, DD, z, DD, nullptr, z, y, scal, mom,
            BNROWS, DD, DS);
    }

    // ---- final recon = z @ D^T -> out ----
    gemm_kernel<64, 128, 0, true><<<dim3(10, 32), 256, 0, stream>>>(
        z, DD, D, DD, out, DS, nullptr, nullptr, nullptr, nullptr, 0.0f,
        BNROWS, DS, DD);
}

// Round 2
// 4730.556 us; speedup vs baseline: 2.3232x; 2.3232x over previous
//
#include <hip/hip_runtime.h>
#include <hip/hip_bf16.h>
#include <cmath>

// ---------------------------------------------------------------------------
// Sizes (fixed by the problem)
// ---------------------------------------------------------------------------
#define DS 1200     // signal dim (recon cols)
#define DD 2400     // dict dim (code cols)
#define MR 2048     // rows (B*N)
#define KP 1216     // padded K for GEMM2 / r stride (1200 -> 38*32)
#define NP1 1280    // padded rows of D panel   (GEMM1/final B, 10*128)
#define NP2 2432    // padded rows of Dt panel  (GEMM2 B, 19*128)

typedef __attribute__((ext_vector_type(8))) short s16x8;
typedef __attribute__((ext_vector_type(4))) float f32x4;

// ---------------------------------------------------------------------------
// JAX threefry2x32 + XLA f32 erfinv (reproduce jax.random.normal(key(42)))
// ---------------------------------------------------------------------------
__device__ __forceinline__ unsigned rotl32(unsigned x, int d) {
    return (x << d) | (x >> (32 - d));
}

__device__ void threefry2x32(unsigned k0, unsigned k1, unsigned x0, unsigned x1,
                             unsigned* o0, unsigned* o1) {
    unsigned ks0 = k0, ks1 = k1, ks2 = k0 ^ k1 ^ 0x1BD11BDAu;
    const int rotA[4] = {13, 15, 26, 6};
    const int rotB[4] = {17, 29, 16, 24};
    x0 += ks0; x1 += ks1;
    #pragma unroll
    for (int r = 0; r < 4; r++) { x0 += x1; x1 = rotl32(x1, rotA[r]); x1 ^= x0; }
    x0 += ks1; x1 += ks2 + 1u;
    #pragma unroll
    for (int r = 0; r < 4; r++) { x0 += x1; x1 = rotl32(x1, rotB[r]); x1 ^= x0; }
    x0 += ks2; x1 += ks0 + 2u;
    #pragma unroll
    for (int r = 0; r < 4; r++) { x0 += x1; x1 = rotl32(x1, rotA[r]); x1 ^= x0; }
    x0 += ks0; x1 += ks1 + 3u;
    #pragma unroll
    for (int r = 0; r < 4; r++) { x0 += x1; x1 = rotl32(x1, rotB[r]); x1 ^= x0; }
    x0 += ks1; x1 += ks2 + 4u;
    #pragma unroll
    for (int r = 0; r < 4; r++) { x0 += x1; x1 = rotl32(x1, rotA[r]); x1 ^= x0; }
    x0 += ks2; x1 += ks0 + 5u;
    *o0 = x0; *o1 = x1;
}

__device__ float erfinv_f32(float x) {
    float w = -logf((1.0f - x) * (1.0f + x));
    float p;
    if (w < 5.0f) {
        w -= 2.5f;
        p = 2.81022636e-08f;
        p = fmaf(p, w, 3.43273939e-07f);
        p = fmaf(p, w, -3.5233877e-06f);
        p = fmaf(p, w, -4.39150654e-06f);
        p = fmaf(p, w, 0.00021858087f);
        p = fmaf(p, w, -0.00125372503f);
        p = fmaf(p, w, -0.00417768164f);
        p = fmaf(p, w, 0.246640727f);
        p = fmaf(p, w, 1.50140941f);
    } else {
        w = sqrtf(w) - 3.0f;
        p = -0.000200214257f;
        p = fmaf(p, w, 0.000100950558f);
        p = fmaf(p, w, 0.00134934322f);
        p = fmaf(p, w, -0.00367342844f);
        p = fmaf(p, w, 0.00573950773f);
        p = fmaf(p, w, -0.0076224613f);
        p = fmaf(p, w, 0.00943887047f);
        p = fmaf(p, w, 1.00167406f);
        p = fmaf(p, w, 2.83297682f);
    }
    return p * x;
}

__device__ float bits_to_normal(unsigned bits) {
    unsigned fb = (bits >> 9) | 0x3F800000u;
    float u01 = __uint_as_float(fb) - 1.0f;
    const float lo = -0.99999994f;
    float u = u01 * 2.0f + lo;
    u = fmaxf(lo, u);
    return 1.41421356237f * erfinv_f32(u);
}

// ---------------------------------------------------------------------------
// Power iteration (deterministic, fixed-slot partials)
// ---------------------------------------------------------------------------
__global__ void k_init(float* __restrict__ wbuf, float* __restrict__ part) {
    int tid = threadIdx.x;
    for (int i = tid; i < 21 * 10; i += 256) part[i] = 0.0f;
    __shared__ float red[256];
    float local2 = 0.0f;
    for (int p = tid; p < DS; p += 256) {
        unsigned r0, r1;
        threefry2x32(0u, 42u, (unsigned)p, (unsigned)(DS + p), &r0, &r1);
        float n0 = bits_to_normal(r0);
        float n1 = bits_to_normal(r1);
        wbuf[p] = n0;
        wbuf[DS + p] = n1;
        local2 += n0 * n0 + n1 * n1;
    }
    red[tid] = local2;
    __syncthreads();
    for (int s = 128; s > 0; s >>= 1) {
        if (tid < s) red[tid] += red[tid + s];
        __syncthreads();
    }
    if (tid == 0) part[0] = red[0];
}

__global__ __launch_bounds__(256) void k_mv_rows(const float* __restrict__ D,
                                                 const float* __restrict__ w,
                                                 const float* __restrict__ part,
                                                 float* __restrict__ u) {
    float s2 = 0.0f;
    #pragma unroll
    for (int i = 0; i < 10; i++) s2 += part[i];
    float rn = 1.0f / sqrtf(s2);
    int wave = threadIdx.x >> 6;
    int lane = threadIdx.x & 63;
    int row = blockIdx.x * 4 + wave;
    const float4* Dr = (const float4*)(D + (size_t)row * DD);
    const float4* w4p = (const float4*)w;
    float acc = 0.0f;
    #pragma unroll
    for (int i = 0; i < 10; i++) {
        int c4 = lane + i * 64;
        if (c4 < 600) {
            float4 d4 = Dr[c4];
            float4 w4 = w4p[c4];
            acc += d4.x * w4.x + d4.y * w4.y + d4.z * w4.z + d4.w * w4.w;
        }
    }
    #pragma unroll
    for (int off = 32; off > 0; off >>= 1) acc += __shfl_xor(acc, off, 64);
    if (lane == 0) u[row] = acc * rn;
}

__global__ __launch_bounds__(256) void k_mv_cols(const float* __restrict__ D,
                                                 const float* __restrict__ u,
                                                 float* __restrict__ w,
                                                 float* __restrict__ part_out) {
    __shared__ float us[DS];
    __shared__ float red[256];
    int tid = threadIdx.x;
    for (int i = tid; i < DS; i += 256) us[i] = u[i];
    __syncthreads();
    int k = blockIdx.x * 256 + tid;
    const float* Dk = D + k;
    float acc = 0.0f;
    #pragma unroll 4
    for (int d = 0; d < DS; d++) acc = fmaf(Dk[(size_t)d * DD], us[d], acc);
    w[k] = acc;
    red[tid] = acc * acc;
    __syncthreads();
    for (int s = 128; s > 0; s >>= 1) {
        if (tid < s) red[tid] += red[tid + s];
        __syncthreads();
    }
    if (tid == 0) part_out[blockIdx.x] = red[0];
}

__global__ void k_fin(const float* __restrict__ part20, float* __restrict__ scal) {
    if (threadIdx.x == 0) {
        float s = 0.0f;
        for (int i = 0; i < 10; i++) s += part20[i];
        float L = sqrtf(s);
        scal[0] = L;
        scal[1] = 1.0f / L;
        scal[2] = 0.1f / L;
    }
}

// ---------------------------------------------------------------------------
// Prep kernels: split D into bf16 hi/lo (row-major padded, and transposed)
// ---------------------------------------------------------------------------
__global__ void k_makeD(const float* __restrict__ D,
                        __hip_bfloat16* __restrict__ Dhi,
                        __hip_bfloat16* __restrict__ Dlo) {
    int i = blockIdx.x * 256 + threadIdx.x;   // over NP1*DD
    if (i >= NP1 * DD) return;
    int r = i / DD;
    float v = (r < DS) ? D[i] : 0.0f;
    __hip_bfloat16 h = __float2bfloat16(v);
    Dhi[i] = h;
    Dlo[i] = __float2bfloat16(v - __bfloat162float(h));
}

__global__ void k_makeDt(const float* __restrict__ D,
                         __hip_bfloat16* __restrict__ Dthi,
                         __hip_bfloat16* __restrict__ Dtlo) {
    __shared__ float t[32][33];
    int bc = blockIdx.x * 32;   // dict-col base (Dt row), 0..2432
    int bk = blockIdx.y * 32;   // signal-row base (Dt col), 0..1216
    int tx = threadIdx.x & 31, ty = threadIdx.x >> 5;  // 256 thr: ty 0..7
    for (int i = ty; i < 32; i += 8) {
        int k = bk + i, c = bc + tx;
        t[i][tx] = (k < DS && c < DD) ? D[(size_t)k * DD + c] : 0.0f;
    }
    __syncthreads();
    for (int i = ty; i < 32; i += 8) {
        int c = bc + i, k = bk + tx;
        if (c < NP2 && k < KP) {
            float v = t[tx][i];
            __hip_bfloat16 h = __float2bfloat16(v);
            size_t o = (size_t)c * KP + k;
            Dthi[o] = h;
            Dtlo[o] = __float2bfloat16(v - __bfloat162float(h));
        }
    }
}

__global__ void k_zero_s(s16x8* __restrict__ p, int n8) {
    int i = blockIdx.x * blockDim.x + threadIdx.x;
    if (i < n8) {
        s16x8 z = {0, 0, 0, 0, 0, 0, 0, 0};
        p[i] = z;
    }
}

// ---------------------------------------------------------------------------
// Split-bf16 MFMA GEMM: C[m][n] = sum_k (Ahi+Alo)[m][k] * (Bhi+Blo)[n][k]
// (drops lo*lo term: ~2^-16 relative precision)
// Tile 64(M) x 128(N), BK=32, 4 waves (each 32x64), 16x16x32 bf16 MFMA.
// EPI 0: Out[m*DS+n] = acc                      (final recon, n < DS)
// EPI 1: r = acc - X; write split Rhi/Rlo       (n < KP; X only n < DS)
// EPI 2: FISTA update on split Z/Y              (n < DD)
// ---------------------------------------------------------------------------
__device__ __forceinline__ void gload16(const void* g, void* l) {
    __builtin_amdgcn_global_load_lds(
        (const __attribute__((address_space(1))) unsigned int*)g,
        (__attribute__((address_space(3))) unsigned int*)l, 16, 0, 0);
}

template <int EPI>
__global__ __launch_bounds__(256) void mfma_gemm(
    const __hip_bfloat16* __restrict__ Ahi, const __hip_bfloat16* __restrict__ Alo, int lda,
    const __hip_bfloat16* __restrict__ Bhi, const __hip_bfloat16* __restrict__ Blo, int ldb,
    int K,
    const float* __restrict__ X,
    __hip_bfloat16* __restrict__ Rhi, __hip_bfloat16* __restrict__ Rlo,
    __hip_bfloat16* __restrict__ Zhi, __hip_bfloat16* __restrict__ Zlo,
    __hip_bfloat16* __restrict__ Yhi, __hip_bfloat16* __restrict__ Ylo,
    const float* __restrict__ scal, float mom,
    float* __restrict__ Out) {
    __shared__ __align__(16) short Ash[64 * 32], Asl[64 * 32];
    __shared__ __align__(16) short Bsh[128 * 32], Bsl[128 * 32];

    const int tid = threadIdx.x;
    const int w = tid >> 6, lane = tid & 63;
    const int m0 = blockIdx.y * 64, n0 = blockIdx.x * 128;
    const int srow = lane >> 2, sk = (lane & 3) * 8;   // staging: 16 rows/call
    const int fm = lane & 15, kg = lane >> 4;          // fragment addressing
    const int wr = w >> 1, wc = w & 1;                 // wave tile 32x64

    f32x4 acc[2][4];
    #pragma unroll
    for (int g = 0; g < 2; ++g)
        #pragma unroll
        for (int h = 0; h < 4; ++h) acc[g][h] = f32x4{0.f, 0.f, 0.f, 0.f};

    float invL = 0.0f, thr = 0.0f;
    if (EPI == 2) { invL = scal[1]; thr = scal[2]; }

    // wave-uniform LDS staging bases; per-lane global offsets
    const size_t arow = (size_t)(m0 + w * 16 + srow) * lda + sk;
    const size_t brow0 = (size_t)(n0 + w * 32 + srow) * ldb + sk;
    const size_t brow1 = (size_t)(n0 + w * 32 + 16 + srow) * ldb + sk;
    short* ldsAh = &Ash[(w * 16) * 32];
    short* ldsAl = &Asl[(w * 16) * 32];
    short* ldsBh0 = &Bsh[(w * 32) * 32];
    short* ldsBl0 = &Bsl[(w * 32) * 32];
    short* ldsBh1 = &Bsh[(w * 32 + 16) * 32];
    short* ldsBl1 = &Bsl[(w * 32 + 16) * 32];

    for (int k0 = 0; k0 < K; k0 += 32) {
        gload16(Ahi + arow + k0, ldsAh);
        gload16(Alo + arow + k0, ldsAl);
        gload16(Bhi + brow0 + k0, ldsBh0);
        gload16(Blo + brow0 + k0, ldsBl0);
        gload16(Bhi + brow1 + k0, ldsBh1);
        gload16(Blo + brow1 + k0, ldsBl1);
        __syncthreads();

        s16x8 ah[2], al[2], bh[4], bl[4];
        #pragma unroll
        for (int g = 0; g < 2; ++g) {
            int r = wr * 32 + g * 16 + fm;
            ah[g] = *(const s16x8*)&Ash[r * 32 + kg * 8];
            al[g] = *(const s16x8*)&Asl[r * 32 + kg * 8];
        }
        #pragma unroll
        for (int h = 0; h < 4; ++h) {
            int c = wc * 64 + h * 16 + fm;
            bh[h] = *(const s16x8*)&Bsh[c * 32 + kg * 8];
            bl[h] = *(const s16x8*)&Bsl[c * 32 + kg * 8];
        }
        #pragma unroll
        for (int g = 0; g < 2; ++g)
            #pragma unroll
            for (int h = 0; h < 4; ++h) {
                acc[g][h] = __builtin_amdgcn_mfma_f32_16x16x32_bf16(ah[g], bh[h], acc[g][h], 0, 0, 0);
                acc[g][h] = __builtin_amdgcn_mfma_f32_16x16x32_bf16(ah[g], bl[h], acc[g][h], 0, 0, 0);
                acc[g][h] = __builtin_amdgcn_mfma_f32_16x16x32_bf16(al[g], bh[h], acc[g][h], 0, 0, 0);
            }
        __syncthreads();
    }

    // epilogue: C row = kg*4 + j (within frag), col = fm  [measured m89/m91]
    #pragma unroll
    for (int g = 0; g < 2; ++g) {
        #pragma unroll
        for (int h = 0; h < 4; ++h) {
            #pragma unroll
            for (int j = 0; j < 4; ++j) {
                int m = m0 + wr * 32 + g * 16 + kg * 4 + j;
                int n = n0 + wc * 64 + h * 16 + fm;
                float v = acc[g][h][j];
                if (EPI == 0) {
                    if (n < DS) Out[(size_t)m * DS + n] = v;
                } else if (EPI == 1) {
                    if (n < KP) {
                        if (n < DS) v -= X[(size_t)m * DS + n];
                        __hip_bfloat16 hb = __float2bfloat16(v);
                        size_t o = (size_t)m * KP + n;
                        Rhi[o] = hb;
                        Rlo[o] = __float2bfloat16(v - __bfloat162float(hb));
                    }
                } else {
                    if (n < DD) {
                        size_t o = (size_t)m * DD + n;
                        float yold = __bfloat162float(Yhi[o]) + __bfloat162float(Ylo[o]);
                        float zold = __bfloat162float(Zhi[o]) + __bfloat162float(Zlo[o]);
                        float gs = yold - v * invL;
                        float az = fabsf(gs) - thr;
                        float zn = (az > 0.0f) ? copysignf(az, gs) : 0.0f;
                        float yn = zn + mom * (zn - zold);
                        __hip_bfloat16 zh = __float2bfloat16(zn);
                        Zhi[o] = zh;
                        Zlo[o] = __float2bfloat16(zn - __bfloat162float(zh));
                        __hip_bfloat16 yh = __float2bfloat16(yn);
                        Yhi[o] = yh;
                        Ylo[o] = __float2bfloat16(yn - __bfloat162float(yh));
                    }
                }
            }
        }
    }
}

// ---------------------------------------------------------------------------
// Launch
// ---------------------------------------------------------------------------
extern "C" void kernel_launch(void* const* d_in, const int* in_sizes, int n_in,
                              void* d_out, int out_size, void* d_ws, size_t ws_size,
                              hipStream_t stream) {
    const float* x = (const float*)d_in[0];   // (2048, 1200)
    const float* D = (const float*)d_in[1];   // (1200, 2400)
    float* out = (float*)d_out;               // (2048, 1200)

    char* wsb = (char*)d_ws;
    float* wbuf = (float*)wsb;                // 2400
    float* u = wbuf + 2400;                   // 1200
    float* part = u + 1200;                   // 210
    float* scal = part + 256;                 // 3

    __hip_bfloat16* Dhi = (__hip_bfloat16*)(wsb + 65536);
    __hip_bfloat16* Dlo = Dhi + (size_t)NP1 * DD;
    __hip_bfloat16* Dthi = Dlo + (size_t)NP1 * DD;
    __hip_bfloat16* Dtlo = Dthi + (size_t)NP2 * KP;
    __hip_bfloat16* Yhi = Dtlo + (size_t)NP2 * KP;   // Y,Z contiguous for zeroing
    __hip_bfloat16* Ylo = Yhi + (size_t)MR * DD;
    __hip_bfloat16* Zhi = Ylo + (size_t)MR * DD;
    __hip_bfloat16* Zlo = Zhi + (size_t)MR * DD;
    __hip_bfloat16* Rhi = Zlo + (size_t)MR * DD;
    __hip_bfloat16* Rlo = Rhi + (size_t)MR * KP;

    // ---- power iteration for L ----
    k_init<<<1, 256, 0, stream>>>(wbuf, part);
    for (int j = 0; j < 20; j++) {
        k_mv_rows<<<300, 256, 0, stream>>>(D, wbuf, part + j * 10, u);
        k_mv_cols<<<10, 256, 0, stream>>>(D, u, wbuf, part + (j + 1) * 10);
    }
    k_fin<<<1, 64, 0, stream>>>(part + 200, scal);

    // ---- split D (row-major padded + transposed padded) ----
    k_makeD<<<(NP1 * DD + 255) / 256, 256, 0, stream>>>(D, Dhi, Dlo);
    k_makeDt<<<dim3(NP2 / 32, KP / 32), 256, 0, stream>>>(D, Dthi, Dtlo);

    // ---- zero Y,Z (hi/lo) ----
    {
        int n8 = 4 * MR * DD / 8;
        k_zero_s<<<(n8 + 255) / 256, 256, 0, stream>>>((s16x8*)Yhi, n8);
    }

    // ---- FISTA ----
    float t = 1.0f;
    for (int i = 0; i < 16; i++) {
        float tn = 0.5f * (1.0f + sqrtf(1.0f + 4.0f * t * t));
        float mom = (t - 1.0f) / tn;
        t = tn;
        // r = y @ D^T - x2  -> split Rhi/Rlo   (M=2048, N=1200(->1216), K=2400)
        mfma_gemm<1><<<dim3(NP1 / 128, MR / 64), 256, 0, stream>>>(
            Yhi, Ylo, DD, Dhi, Dlo, DD, DD,
            x, Rhi, Rlo, nullptr, nullptr, nullptr, nullptr, nullptr, 0.0f, nullptr);
        // grad = r @ D; FISTA update on split Z/Y  (M=2048, N=2400, K=1216)
        mfma_gemm<2><<<dim3(NP2 / 128, MR / 64), 256, 0, stream>>>(
            Rhi, Rlo, KP, Dthi, Dtlo, KP, KP,
            nullptr, nullptr, nullptr, Zhi, Zlo, Yhi, Ylo, scal, mom, nullptr);
    }

    // ---- final recon = z @ D^T -> out ----
    mfma_gemm<0><<<dim3(NP1 / 128, MR / 64), 256, 0, stream>>>(
        Zhi, Zlo, DD, Dhi, Dlo, DD, DD,
        nullptr, nullptr, nullptr, nullptr, nullptr, nullptr, nullptr, nullptr, 0.0f, out);
}

// Round 3
// 3001.996 us; speedup vs baseline: 3.6609x; 1.5758x over previous
//
#include <hip/hip_runtime.h>
#include <hip/hip_bf16.h>
#include <cmath>

// ---------------------------------------------------------------------------
// Sizes (fixed by the problem)
// ---------------------------------------------------------------------------
#define DS 1200     // signal dim (recon cols)
#define DD 2400     // dict dim (code cols)
#define MR 2048     // rows (B*N)
#define KP 1216     // padded K for GEMM2 / r stride (1200 -> 38*32)
#define NP1 1280    // padded rows of D panel   (GEMM1/final B, 10*128)
#define NP2 2432    // padded rows of Dt panel  (GEMM2 B, 19*128)
#define PPI 150     // norm partials per power iteration

typedef __attribute__((ext_vector_type(8))) short s16x8;
typedef __attribute__((ext_vector_type(4))) float f32x4;

// ---------------------------------------------------------------------------
// JAX threefry2x32 + XLA f32 erfinv (reproduce jax.random.normal(key(42)))
// ---------------------------------------------------------------------------
__device__ __forceinline__ unsigned rotl32(unsigned x, int d) {
    return (x << d) | (x >> (32 - d));
}

__device__ void threefry2x32(unsigned k0, unsigned k1, unsigned x0, unsigned x1,
                             unsigned* o0, unsigned* o1) {
    unsigned ks0 = k0, ks1 = k1, ks2 = k0 ^ k1 ^ 0x1BD11BDAu;
    const int rotA[4] = {13, 15, 26, 6};
    const int rotB[4] = {17, 29, 16, 24};
    x0 += ks0; x1 += ks1;
    #pragma unroll
    for (int r = 0; r < 4; r++) { x0 += x1; x1 = rotl32(x1, rotA[r]); x1 ^= x0; }
    x0 += ks1; x1 += ks2 + 1u;
    #pragma unroll
    for (int r = 0; r < 4; r++) { x0 += x1; x1 = rotl32(x1, rotB[r]); x1 ^= x0; }
    x0 += ks2; x1 += ks0 + 2u;
    #pragma unroll
    for (int r = 0; r < 4; r++) { x0 += x1; x1 = rotl32(x1, rotA[r]); x1 ^= x0; }
    x0 += ks0; x1 += ks1 + 3u;
    #pragma unroll
    for (int r = 0; r < 4; r++) { x0 += x1; x1 = rotl32(x1, rotB[r]); x1 ^= x0; }
    x0 += ks1; x1 += ks2 + 4u;
    #pragma unroll
    for (int r = 0; r < 4; r++) { x0 += x1; x1 = rotl32(x1, rotA[r]); x1 ^= x0; }
    x0 += ks2; x1 += ks0 + 5u;
    *o0 = x0; *o1 = x1;
}

__device__ float erfinv_f32(float x) {
    float w = -logf((1.0f - x) * (1.0f + x));
    float p;
    if (w < 5.0f) {
        w -= 2.5f;
        p = 2.81022636e-08f;
        p = fmaf(p, w, 3.43273939e-07f);
        p = fmaf(p, w, -3.5233877e-06f);
        p = fmaf(p, w, -4.39150654e-06f);
        p = fmaf(p, w, 0.00021858087f);
        p = fmaf(p, w, -0.00125372503f);
        p = fmaf(p, w, -0.00417768164f);
        p = fmaf(p, w, 0.246640727f);
        p = fmaf(p, w, 1.50140941f);
    } else {
        w = sqrtf(w) - 3.0f;
        p = -0.000200214257f;
        p = fmaf(p, w, 0.000100950558f);
        p = fmaf(p, w, 0.00134934322f);
        p = fmaf(p, w, -0.00367342844f);
        p = fmaf(p, w, 0.00573950773f);
        p = fmaf(p, w, -0.0076224613f);
        p = fmaf(p, w, 0.00943887047f);
        p = fmaf(p, w, 1.00167406f);
        p = fmaf(p, w, 2.83297682f);
    }
    return p * x;
}

__device__ float bits_to_normal(unsigned bits) {
    unsigned fb = (bits >> 9) | 0x3F800000u;
    float u01 = __uint_as_float(fb) - 1.0f;
    const float lo = -0.99999994f;
    float u = u01 * 2.0f + lo;
    u = fmaxf(lo, u);
    return 1.41421356237f * erfinv_f32(u);
}

// ---------------------------------------------------------------------------
// Power iteration pieces (deterministic, fixed-slot partials)
// ---------------------------------------------------------------------------
__global__ void k_init(float* __restrict__ wbuf, float* __restrict__ part) {
    int tid = threadIdx.x;
    for (int i = tid; i < 21 * PPI; i += 256) part[i] = 0.0f;
    __shared__ float red[256];
    float local2 = 0.0f;
    for (int p = tid; p < DS; p += 256) {
        unsigned r0, r1;
        threefry2x32(0u, 42u, (unsigned)p, (unsigned)(DS + p), &r0, &r1);
        float n0 = bits_to_normal(r0);
        float n1 = bits_to_normal(r1);
        wbuf[p] = n0;
        wbuf[DS + p] = n1;
        local2 += n0 * n0 + n1 * n1;
    }
    red[tid] = local2;
    __syncthreads();
    for (int s = 128; s > 0; s >>= 1) {
        if (tid < s) red[tid] += red[tid + s];
        __syncthreads();
    }
    if (tid == 0) part[0] = red[0];
}

// wout = (G @ win) * rsqrt(sum(partin)); partout[b] = block partial of ||wout||^2
__global__ __launch_bounds__(1024) void k_gmv(const float* __restrict__ G,
                                              const float* __restrict__ win,
                                              const float* __restrict__ partin,
                                              float* __restrict__ wout,
                                              float* __restrict__ partout) {
    float s2 = 0.0f;
    for (int i = 0; i < PPI; i++) s2 += partin[i];
    float rn = 1.0f / sqrtf(s2);
    int wave = threadIdx.x >> 6, lane = threadIdx.x & 63;
    int row = blockIdx.x * 16 + wave;       // 150 blocks * 16 waves = 2400 rows
    const float4* Gr = (const float4*)(G + (size_t)row * DD);
    const float4* w4 = (const float4*)win;
    float acc = 0.0f;
    #pragma unroll
    for (int i = 0; i < 10; i++) {
        int c = lane + i * 64;              // 600 float4 per row
        if (c < 600) {
            float4 g = Gr[c], v = w4[c];
            acc += g.x * v.x + g.y * v.y + g.z * v.z + g.w * v.w;
        }
    }
    #pragma unroll
    for (int off = 32; off > 0; off >>= 1) acc += __shfl_xor(acc, off, 64);
    __shared__ float red[16];
    if (lane == 0) {
        float val = acc * rn;
        wout[row] = val;
        red[wave] = val * val;
    }
    __syncthreads();
    if (threadIdx.x == 0) {
        float s = 0.0f;
        #pragma unroll
        for (int i = 0; i < 16; i++) s += red[i];
        partout[blockIdx.x] = s;
    }
}

__global__ void k_fin(const float* __restrict__ part20, float* __restrict__ scal) {
    if (threadIdx.x == 0) {
        float s = 0.0f;
        for (int i = 0; i < PPI; i++) s += part20[i];
        float L = sqrtf(s);
        scal[0] = L;
        scal[1] = 1.0f / L;
        scal[2] = 0.1f / L;
    }
}

// ---------------------------------------------------------------------------
// Prep kernels: split D into bf16 hi/lo (row-major padded, and transposed)
// ---------------------------------------------------------------------------
__global__ void k_makeD(const float* __restrict__ D,
                        __hip_bfloat16* __restrict__ Dhi,
                        __hip_bfloat16* __restrict__ Dlo) {
    int i = blockIdx.x * 256 + threadIdx.x;   // over NP1*DD
    if (i >= NP1 * DD) return;
    int r = i / DD;
    float v = (r < DS) ? D[i] : 0.0f;
    __hip_bfloat16 h = __float2bfloat16(v);
    Dhi[i] = h;
    Dlo[i] = __float2bfloat16(v - __bfloat162float(h));
}

__global__ void k_makeDt(const float* __restrict__ D,
                         __hip_bfloat16* __restrict__ Dthi,
                         __hip_bfloat16* __restrict__ Dtlo) {
    __shared__ float t[32][33];
    int bc = blockIdx.x * 32;   // dict-col base (Dt row)
    int bk = blockIdx.y * 32;   // signal-row base (Dt col)
    int tx = threadIdx.x & 31, ty = threadIdx.x >> 5;
    for (int i = ty; i < 32; i += 8) {
        int k = bk + i, c = bc + tx;
        t[i][tx] = (k < DS && c < DD) ? D[(size_t)k * DD + c] : 0.0f;
    }
    __syncthreads();
    for (int i = ty; i < 32; i += 8) {
        int c = bc + i, k = bk + tx;
        if (c < NP2 && k < KP) {
            float v = t[tx][i];
            __hip_bfloat16 h = __float2bfloat16(v);
            size_t o = (size_t)c * KP + k;
            Dthi[o] = h;
            Dtlo[o] = __float2bfloat16(v - __bfloat162float(h));
        }
    }
}

__global__ void k_zero_s(s16x8* __restrict__ p, int n8) {
    int i = blockIdx.x * blockDim.x + threadIdx.x;
    if (i < n8) {
        s16x8 z = {0, 0, 0, 0, 0, 0, 0, 0};
        p[i] = z;
    }
}

// ---------------------------------------------------------------------------
// Split-bf16 MFMA GEMM: C[m][n] = sum_k (Ahi+Alo)[m][k] * (Bhi+Blo)[n][k]
// Tile 64(M) x 128(N), BK=32, 4 waves (each 32x64), 16x16x32 bf16 MFMA.
// EPI 0: Out[m*DS+n] = acc                      (final recon, n < DS)
// EPI 1: r = acc - X; write split Rhi/Rlo       (n < KP; X only n < DS)
// EPI 2: FISTA update on split Z/Y              (n < DD)
// EPI 3: Out[m*DD+n] = acc (fp32 G = Dt @ Dt^T) (m,n < DD)
// ---------------------------------------------------------------------------
__device__ __forceinline__ void gload16(const void* g, void* l) {
    __builtin_amdgcn_global_load_lds(
        (const __attribute__((address_space(1))) unsigned int*)g,
        (__attribute__((address_space(3))) unsigned int*)l, 16, 0, 0);
}

template <int EPI>
__global__ __launch_bounds__(256) void mfma_gemm(
    const __hip_bfloat16* __restrict__ Ahi, const __hip_bfloat16* __restrict__ Alo, int lda,
    const __hip_bfloat16* __restrict__ Bhi, const __hip_bfloat16* __restrict__ Blo, int ldb,
    int K,
    const float* __restrict__ X,
    __hip_bfloat16* __restrict__ Rhi, __hip_bfloat16* __restrict__ Rlo,
    __hip_bfloat16* __restrict__ Zhi, __hip_bfloat16* __restrict__ Zlo,
    __hip_bfloat16* __restrict__ Yhi, __hip_bfloat16* __restrict__ Ylo,
    const float* __restrict__ scal, float mom,
    float* __restrict__ Out) {
    __shared__ __align__(16) short Ash[64 * 32], Asl[64 * 32];
    __shared__ __align__(16) short Bsh[128 * 32], Bsl[128 * 32];

    const int tid = threadIdx.x;
    const int w = tid >> 6, lane = tid & 63;
    const int m0 = blockIdx.y * 64, n0 = blockIdx.x * 128;
    const int srow = lane >> 2, sk = (lane & 3) * 8;   // staging: 16 rows/call
    const int fm = lane & 15, kg = lane >> 4;          // fragment addressing
    const int wr = w >> 1, wc = w & 1;                 // wave tile 32x64

    f32x4 acc[2][4];
    #pragma unroll
    for (int g = 0; g < 2; ++g)
        #pragma unroll
        for (int h = 0; h < 4; ++h) acc[g][h] = f32x4{0.f, 0.f, 0.f, 0.f};

    float invL = 0.0f, thr = 0.0f;
    if (EPI == 2) { invL = scal[1]; thr = scal[2]; }

    const size_t arow = (size_t)(m0 + w * 16 + srow) * lda + sk;
    const size_t brow0 = (size_t)(n0 + w * 32 + srow) * ldb + sk;
    const size_t brow1 = (size_t)(n0 + w * 32 + 16 + srow) * ldb + sk;
    short* ldsAh = &Ash[(w * 16) * 32];
    short* ldsAl = &Asl[(w * 16) * 32];
    short* ldsBh0 = &Bsh[(w * 32) * 32];
    short* ldsBl0 = &Bsl[(w * 32) * 32];
    short* ldsBh1 = &Bsh[(w * 32 + 16) * 32];
    short* ldsBl1 = &Bsl[(w * 32 + 16) * 32];

    for (int k0 = 0; k0 < K; k0 += 32) {
        gload16(Ahi + arow + k0, ldsAh);
        gload16(Alo + arow + k0, ldsAl);
        gload16(Bhi + brow0 + k0, ldsBh0);
        gload16(Blo + brow0 + k0, ldsBl0);
        gload16(Bhi + brow1 + k0, ldsBh1);
        gload16(Blo + brow1 + k0, ldsBl1);
        __syncthreads();

        s16x8 ah[2], al[2], bh[4], bl[4];
        #pragma unroll
        for (int g = 0; g < 2; ++g) {
            int r = wr * 32 + g * 16 + fm;
            ah[g] = *(const s16x8*)&Ash[r * 32 + kg * 8];
            al[g] = *(const s16x8*)&Asl[r * 32 + kg * 8];
        }
        #pragma unroll
        for (int h = 0; h < 4; ++h) {
            int c = wc * 64 + h * 16 + fm;
            bh[h] = *(const s16x8*)&Bsh[c * 32 + kg * 8];
            bl[h] = *(const s16x8*)&Bsl[c * 32 + kg * 8];
        }
        #pragma unroll
        for (int g = 0; g < 2; ++g)
            #pragma unroll
            for (int h = 0; h < 4; ++h) {
                acc[g][h] = __builtin_amdgcn_mfma_f32_16x16x32_bf16(ah[g], bh[h], acc[g][h], 0, 0, 0);
                acc[g][h] = __builtin_amdgcn_mfma_f32_16x16x32_bf16(ah[g], bl[h], acc[g][h], 0, 0, 0);
                acc[g][h] = __builtin_amdgcn_mfma_f32_16x16x32_bf16(al[g], bh[h], acc[g][h], 0, 0, 0);
            }
        __syncthreads();
    }

    // epilogue: C row = kg*4 + j (within frag), col = fm
    #pragma unroll
    for (int g = 0; g < 2; ++g) {
        #pragma unroll
        for (int h = 0; h < 4; ++h) {
            #pragma unroll
            for (int j = 0; j < 4; ++j) {
                int m = m0 + wr * 32 + g * 16 + kg * 4 + j;
                int n = n0 + wc * 64 + h * 16 + fm;
                float v = acc[g][h][j];
                if (EPI == 0) {
                    if (n < DS) Out[(size_t)m * DS + n] = v;
                } else if (EPI == 1) {
                    if (n < KP) {
                        if (n < DS) v -= X[(size_t)m * DS + n];
                        __hip_bfloat16 hb = __float2bfloat16(v);
                        size_t o = (size_t)m * KP + n;
                        Rhi[o] = hb;
                        Rlo[o] = __float2bfloat16(v - __bfloat162float(hb));
                    }
                } else if (EPI == 2) {
                    if (n < DD) {
                        size_t o = (size_t)m * DD + n;
                        float yold = __bfloat162float(Yhi[o]) + __bfloat162float(Ylo[o]);
                        float zold = __bfloat162float(Zhi[o]) + __bfloat162float(Zlo[o]);
                        float gs = yold - v * invL;
                        float az = fabsf(gs) - thr;
                        float zn = (az > 0.0f) ? copysignf(az, gs) : 0.0f;
                        float yn = zn + mom * (zn - zold);
                        __hip_bfloat16 zh = __float2bfloat16(zn);
                        Zhi[o] = zh;
                        Zlo[o] = __float2bfloat16(zn - __bfloat162float(zh));
                        __hip_bfloat16 yh = __float2bfloat16(yn);
                        Yhi[o] = yh;
                        Ylo[o] = __float2bfloat16(yn - __bfloat162float(yh));
                    }
                } else {  // EPI == 3: G write
                    if (m < DD && n < DD) Out[(size_t)m * DD + n] = v;
                }
            }
        }
    }
}

// ---------------------------------------------------------------------------
// Launch
// ---------------------------------------------------------------------------
extern "C" void kernel_launch(void* const* d_in, const int* in_sizes, int n_in,
                              void* d_out, int out_size, void* d_ws, size_t ws_size,
                              hipStream_t stream) {
    const float* x = (const float*)d_in[0];   // (2048, 1200)
    const float* D = (const float*)d_in[1];   // (1200, 2400)
    float* out = (float*)d_out;               // (2048, 1200)

    char* wsb = (char*)d_ws;
    float* w0 = (float*)wsb;                  // 2400
    float* w1 = w0 + 2400;                    // 2400
    float* part = w1 + 2400;                  // 21*150 = 3150
    float* scal = part + 3200;                // 3

    float* G = (float*)(wsb + 65536);         // 2400*2400 fp32 = 23.04 MB
    __hip_bfloat16* Dhi = (__hip_bfloat16*)(G + (size_t)DD * DD);
    __hip_bfloat16* Dlo = Dhi + (size_t)NP1 * DD;
    __hip_bfloat16* Dthi = Dlo + (size_t)NP1 * DD;
    __hip_bfloat16* Dtlo = Dthi + (size_t)NP2 * KP;
    __hip_bfloat16* Yhi = Dtlo + (size_t)NP2 * KP;   // Y,Z contiguous for zeroing
    __hip_bfloat16* Ylo = Yhi + (size_t)MR * DD;
    __hip_bfloat16* Zhi = Ylo + (size_t)MR * DD;
    __hip_bfloat16* Zlo = Zhi + (size_t)MR * DD;
    __hip_bfloat16* Rhi = Zlo + (size_t)MR * DD;
    __hip_bfloat16* Rlo = Rhi + (size_t)MR * KP;

    // ---- split D (row-major padded + transposed padded) ----
    k_makeD<<<(NP1 * DD + 255) / 256, 256, 0, stream>>>(D, Dhi, Dlo);
    k_makeDt<<<dim3(NP2 / 32, KP / 32), 256, 0, stream>>>(D, Dthi, Dtlo);

    // ---- G = D^T D via split-bf16 MFMA (A=B=Dt panels, K=1216) ----
    mfma_gemm<3><<<dim3(NP2 / 128, NP2 / 64), 256, 0, stream>>>(
        Dthi, Dtlo, KP, Dthi, Dtlo, KP, KP,
        nullptr, nullptr, nullptr, nullptr, nullptr, nullptr, nullptr,
        nullptr, 0.0f, G);

    // ---- power iteration on G ----
    k_init<<<1, 256, 0, stream>>>(w0, part);
    for (int j = 0; j < 20; j++) {
        const float* win = (j & 1) ? w1 : w0;
        float* wout = (j & 1) ? w0 : w1;
        k_gmv<<<PPI, 1024, 0, stream>>>(G, win, part + j * PPI, wout, part + (j + 1) * PPI);
    }
    k_fin<<<1, 64, 0, stream>>>(part + 20 * PPI, scal);

    // ---- zero Y,Z (hi/lo) ----
    {
        int n8 = 4 * MR * DD / 8;
        k_zero_s<<<(n8 + 255) / 256, 256, 0, stream>>>((s16x8*)Yhi, n8);
    }

    // ---- FISTA ----
    float t = 1.0f;
    for (int i = 0; i < 16; i++) {
        float tn = 0.5f * (1.0f + sqrtf(1.0f + 4.0f * t * t));
        float mom = (t - 1.0f) / tn;
        t = tn;
        // r = y @ D^T - x2  -> split Rhi/Rlo   (M=2048, N=1200(->1280), K=2400)
        mfma_gemm<1><<<dim3(NP1 / 128, MR / 64), 256, 0, stream>>>(
            Yhi, Ylo, DD, Dhi, Dlo, DD, DD,
            x, Rhi, Rlo, nullptr, nullptr, nullptr, nullptr, nullptr, 0.0f, nullptr);
        // grad = r @ D; FISTA update on split Z/Y  (M=2048, N=2400(->2432), K=1216)
        mfma_gemm<2><<<dim3(NP2 / 128, MR / 64), 256, 0, stream>>>(
            Rhi, Rlo, KP, Dthi, Dtlo, KP, KP,
            nullptr, nullptr, nullptr, Zhi, Zlo, Yhi, Ylo, scal, mom, nullptr);
    }

    // ---- final recon = z @ D^T -> out ----
    mfma_gemm<0><<<dim3(NP1 / 128, MR / 64), 256, 0, stream>>>(
        Zhi, Zlo, DD, Dhi, Dlo, DD, DD,
        nullptr, nullptr, nullptr, nullptr, nullptr, nullptr, nullptr, nullptr, 0.0f, out);
}

// Round 4
// 2675.476 us; speedup vs baseline: 4.1077x; 1.1220x over previous
//
#include <hip/hip_runtime.h>
#include <hip/hip_bf16.h>
#include <cmath>

// ---------------------------------------------------------------------------
// Sizes (fixed by the problem)
// ---------------------------------------------------------------------------
#define DS 1200     // signal dim (recon cols)
#define DD 2400     // dict dim (code cols)
#define MR 2048     // rows (B*N)
#define KP 1216     // padded K for D^T panels (1200 -> 38*32)
#define NP1 1280    // padded rows of D panel (recon B, 10*128)
#define NG 2432     // padded dict dim: G size, Y/Z/XD stride (19*128 = 76*32)
#define PPI 150     // norm partials per power iteration

typedef __attribute__((ext_vector_type(8))) short s16x8;
typedef __attribute__((ext_vector_type(4))) float f32x4;

__device__ __forceinline__ float bf2f(__hip_bfloat16 h) {
    return __bfloat162float(h);
}
__device__ __forceinline__ float s2f(short s) {
    union { unsigned u; float f; } c;
    c.u = ((unsigned)(unsigned short)s) << 16;
    return c.f;
}

// ---------------------------------------------------------------------------
// JAX threefry2x32 + XLA f32 erfinv (reproduce jax.random.normal(key(42)))
// ---------------------------------------------------------------------------
__device__ __forceinline__ unsigned rotl32(unsigned x, int d) {
    return (x << d) | (x >> (32 - d));
}

__device__ void threefry2x32(unsigned k0, unsigned k1, unsigned x0, unsigned x1,
                             unsigned* o0, unsigned* o1) {
    unsigned ks0 = k0, ks1 = k1, ks2 = k0 ^ k1 ^ 0x1BD11BDAu;
    const int rotA[4] = {13, 15, 26, 6};
    const int rotB[4] = {17, 29, 16, 24};
    x0 += ks0; x1 += ks1;
    #pragma unroll
    for (int r = 0; r < 4; r++) { x0 += x1; x1 = rotl32(x1, rotA[r]); x1 ^= x0; }
    x0 += ks1; x1 += ks2 + 1u;
    #pragma unroll
    for (int r = 0; r < 4; r++) { x0 += x1; x1 = rotl32(x1, rotB[r]); x1 ^= x0; }
    x0 += ks2; x1 += ks0 + 2u;
    #pragma unroll
    for (int r = 0; r < 4; r++) { x0 += x1; x1 = rotl32(x1, rotA[r]); x1 ^= x0; }
    x0 += ks0; x1 += ks1 + 3u;
    #pragma unroll
    for (int r = 0; r < 4; r++) { x0 += x1; x1 = rotl32(x1, rotB[r]); x1 ^= x0; }
    x0 += ks1; x1 += ks2 + 4u;
    #pragma unroll
    for (int r = 0; r < 4; r++) { x0 += x1; x1 = rotl32(x1, rotA[r]); x1 ^= x0; }
    x0 += ks2; x1 += ks0 + 5u;
    *o0 = x0; *o1 = x1;
}

__device__ float erfinv_f32(float x) {
    float w = -logf((1.0f - x) * (1.0f + x));
    float p;
    if (w < 5.0f) {
        w -= 2.5f;
        p = 2.81022636e-08f;
        p = fmaf(p, w, 3.43273939e-07f);
        p = fmaf(p, w, -3.5233877e-06f);
        p = fmaf(p, w, -4.39150654e-06f);
        p = fmaf(p, w, 0.00021858087f);
        p = fmaf(p, w, -0.00125372503f);
        p = fmaf(p, w, -0.00417768164f);
        p = fmaf(p, w, 0.246640727f);
        p = fmaf(p, w, 1.50140941f);
    } else {
        w = sqrtf(w) - 3.0f;
        p = -0.000200214257f;
        p = fmaf(p, w, 0.000100950558f);
        p = fmaf(p, w, 0.00134934322f);
        p = fmaf(p, w, -0.00367342844f);
        p = fmaf(p, w, 0.00573950773f);
        p = fmaf(p, w, -0.0076224613f);
        p = fmaf(p, w, 0.00943887047f);
        p = fmaf(p, w, 1.00167406f);
        p = fmaf(p, w, 2.83297682f);
    }
    return p * x;
}

__device__ float bits_to_normal(unsigned bits) {
    unsigned fb = (bits >> 9) | 0x3F800000u;
    float u01 = __uint_as_float(fb) - 1.0f;
    const float lo = -0.99999994f;
    float u = u01 * 2.0f + lo;
    u = fmaxf(lo, u);
    return 1.41421356237f * erfinv_f32(u);
}

// ---------------------------------------------------------------------------
// Power iteration pieces (deterministic, fixed-slot partials)
// ---------------------------------------------------------------------------
__global__ void k_init(float* __restrict__ w0, float* __restrict__ w1,
                       float* __restrict__ part) {
    int tid = threadIdx.x;
    for (int i = tid; i < 21 * PPI; i += 256) part[i] = 0.0f;
    if (tid < 32) {                 // zero K-pads of both vectors
        w0[2400 + tid] = 0.0f;
        w1[2400 + tid] = 0.0f;
    }
    __shared__ float red[256];
    float local2 = 0.0f;
    for (int p = tid; p < DS; p += 256) {
        unsigned r0, r1;
        threefry2x32(0u, 42u, (unsigned)p, (unsigned)(DS + p), &r0, &r1);
        float n0 = bits_to_normal(r0);
        float n1 = bits_to_normal(r1);
        w0[p] = n0;
        w0[DS + p] = n1;
        local2 += n0 * n0 + n1 * n1;
    }
    red[tid] = local2;
    __syncthreads();
    for (int s = 128; s > 0; s >>= 1) {
        if (tid < s) red[tid] += red[tid + s];
        __syncthreads();
    }
    if (tid == 0) part[0] = red[0];
}

// wout = (G @ (win * rsqrt(sum partin))); partout[b] = block partial of ||wout||^2
// G given as split bf16 hi/lo, stride NG.
__global__ __launch_bounds__(1024) void k_gmv(const __hip_bfloat16* __restrict__ Ghi,
                                              const __hip_bfloat16* __restrict__ Glo,
                                              const float* __restrict__ win,
                                              const float* __restrict__ partin,
                                              float* __restrict__ wout,
                                              float* __restrict__ partout) {
    float s2 = 0.0f;
    for (int i = 0; i < PPI; i++) s2 += partin[i];
    float rn = 1.0f / sqrtf(s2);
    int wave = threadIdx.x >> 6, lane = threadIdx.x & 63;
    int row = blockIdx.x * 16 + wave;       // 150 blocks * 16 waves = 2400 rows
    const s16x8* gh = (const s16x8*)(Ghi + (size_t)row * NG);
    const s16x8* gl = (const s16x8*)(Glo + (size_t)row * NG);
    const float4* w4 = (const float4*)win;
    float acc = 0.0f;
    #pragma unroll
    for (int i = 0; i < 5; i++) {
        int c = lane + i * 64;              // 304 s16x8 per row
        if (c < 304) {
            s16x8 h = gh[c], l = gl[c];
            float4 wa = w4[c * 2], wb = w4[c * 2 + 1];
            acc += (s2f(h[0]) + s2f(l[0])) * wa.x;
            acc += (s2f(h[1]) + s2f(l[1])) * wa.y;
            acc += (s2f(h[2]) + s2f(l[2])) * wa.z;
            acc += (s2f(h[3]) + s2f(l[3])) * wa.w;
            acc += (s2f(h[4]) + s2f(l[4])) * wb.x;
            acc += (s2f(h[5]) + s2f(l[5])) * wb.y;
            acc += (s2f(h[6]) + s2f(l[6])) * wb.z;
            acc += (s2f(h[7]) + s2f(l[7])) * wb.w;
        }
    }
    #pragma unroll
    for (int off = 32; off > 0; off >>= 1) acc += __shfl_xor(acc, off, 64);
    __shared__ float red[16];
    if (lane == 0) {
        float val = acc * rn;
        wout[row] = val;
        red[wave] = val * val;
    }
    __syncthreads();
    if (threadIdx.x == 0) {
        float s = 0.0f;
        #pragma unroll
        for (int i = 0; i < 16; i++) s += red[i];
        partout[blockIdx.x] = s;
    }
}

__global__ void k_fin(const float* __restrict__ part20, float* __restrict__ scal) {
    if (threadIdx.x == 0) {
        float s = 0.0f;
        for (int i = 0; i < PPI; i++) s += part20[i];
        float L = sqrtf(s);
        scal[0] = L;
        scal[1] = 1.0f / L;
        scal[2] = 0.1f / L;
    }
}

// ---------------------------------------------------------------------------
// Prep kernels
// ---------------------------------------------------------------------------
__global__ void k_makeD(const float* __restrict__ D,
                        __hip_bfloat16* __restrict__ Dhi,
                        __hip_bfloat16* __restrict__ Dlo) {
    int i = blockIdx.x * 256 + threadIdx.x;   // over NP1*NG
    if (i >= NP1 * NG) return;
    int r = i / NG, c = i % NG;
    float v = (r < DS && c < DD) ? D[(size_t)r * DD + c] : 0.0f;
    __hip_bfloat16 h = __float2bfloat16(v);
    Dhi[i] = h;
    Dlo[i] = __float2bfloat16(v - bf2f(h));
}

__global__ void k_makeX(const float* __restrict__ x,
                        __hip_bfloat16* __restrict__ Xhi,
                        __hip_bfloat16* __restrict__ Xlo) {
    int i = blockIdx.x * 256 + threadIdx.x;   // over MR*KP
    if (i >= MR * KP) return;
    int r = i / KP, c = i % KP;
    float v = (c < DS) ? x[(size_t)r * DS + c] : 0.0f;
    __hip_bfloat16 h = __float2bfloat16(v);
    Xhi[i] = h;
    Xlo[i] = __float2bfloat16(v - bf2f(h));
}

__global__ void k_makeDt(const float* __restrict__ D,
                         __hip_bfloat16* __restrict__ Dthi,
                         __hip_bfloat16* __restrict__ Dtlo) {
    __shared__ float t[32][33];
    int bc = blockIdx.x * 32;   // dict-col base (Dt row)
    int bk = blockIdx.y * 32;   // signal-row base (Dt col)
    int tx = threadIdx.x & 31, ty = threadIdx.x >> 5;
    for (int i = ty; i < 32; i += 8) {
        int k = bk + i, c = bc + tx;
        t[i][tx] = (k < DS && c < DD) ? D[(size_t)k * DD + c] : 0.0f;
    }
    __syncthreads();
    for (int i = ty; i < 32; i += 8) {
        int c = bc + i, k = bk + tx;
        float v = t[tx][i];
        __hip_bfloat16 h = __float2bfloat16(v);
        size_t o = (size_t)c * KP + k;
        Dthi[o] = h;
        Dtlo[o] = __float2bfloat16(v - bf2f(h));
    }
}

__global__ void k_zero_s(s16x8* __restrict__ p, int n8) {
    int i = blockIdx.x * blockDim.x + threadIdx.x;
    if (i < n8) {
        s16x8 z = {0, 0, 0, 0, 0, 0, 0, 0};
        p[i] = z;
    }
}

// ---------------------------------------------------------------------------
// Split-bf16 MFMA GEMM, 2-phase double-buffered LDS pipeline.
//   C[m][n] = sum_k (Ahi+Alo)[m][k] * (Bhi+Blo)[n][k]   (lo*lo dropped)
// Tile 64(M) x 128(N), BK=32, 4 waves (each 32x64), 16x16x32 bf16 MFMA.
// EPI 0: Out[m*DS+n] = acc               (final recon, n < DS)
// EPI 2: FISTA: g=acc-XD; z=soft(y-g/L); Ynext=z+mom(z-zold)  (n < DD)
// EPI 3: Out[m*NG+n] = acc fp32          (XD precompute, full padded write)
// EPI 4: split write acc -> Rhi/Rlo      (G precompute, full padded write)
// ---------------------------------------------------------------------------
__device__ __forceinline__ void gload16(const void* g, void* l) {
    __builtin_amdgcn_global_load_lds(
        (const __attribute__((address_space(1))) unsigned int*)g,
        (__attribute__((address_space(3))) unsigned int*)l, 16, 0, 0);
}

#define AH_OFF 0
#define AL_OFF 2048
#define BH_OFF 4096
#define BL_OFF 8192
#define BUF_SZ 12288

template <int EPI>
__global__ __launch_bounds__(256) void mfma_gemm(
    const __hip_bfloat16* __restrict__ Ahi, const __hip_bfloat16* __restrict__ Alo, int lda,
    const __hip_bfloat16* __restrict__ Bhi, const __hip_bfloat16* __restrict__ Blo, int ldb,
    int K,
    const float* __restrict__ XD,
    __hip_bfloat16* __restrict__ Rhi, __hip_bfloat16* __restrict__ Rlo,
    __hip_bfloat16* __restrict__ Zhi, __hip_bfloat16* __restrict__ Zlo,
    const __hip_bfloat16* __restrict__ Yhi, const __hip_bfloat16* __restrict__ Ylo,
    const float* __restrict__ scal, float mom,
    float* __restrict__ Out) {
    __shared__ __align__(16) short lds[2 * BUF_SZ];

    const int tid = threadIdx.x;
    const int w = tid >> 6, lane = tid & 63;
    const int m0 = blockIdx.y * 64, n0 = blockIdx.x * 128;
    const int fm = lane & 15, kg = lane >> 4;          // fragment addressing
    const int wr = w >> 1, wc = w & 1;                 // wave tile 32x64

    f32x4 acc[2][4];
    #pragma unroll
    for (int g = 0; g < 2; ++g)
        #pragma unroll
        for (int h = 0; h < 4; ++h) acc[g][h] = f32x4{0.f, 0.f, 0.f, 0.f};

    float invL = 0.0f, thr = 0.0f;
    if (EPI == 2) { invL = scal[1]; thr = scal[2]; }

    const int srow = lane >> 2, sk = (lane & 3) * 8;
    const size_t arow = (size_t)(m0 + w * 16 + srow) * lda + sk;
    const size_t brow0 = (size_t)(n0 + w * 32 + srow) * ldb + sk;
    const size_t brow1 = (size_t)(n0 + w * 32 + 16 + srow) * ldb + sk;

    const int nk = K >> 5;

    // prologue: stage tile 0 into buffer 0
    {
        short* p = &lds[0];
        gload16(Ahi + arow, p + AH_OFF + w * 512);
        gload16(Alo + arow, p + AL_OFF + w * 512);
        gload16(Bhi + brow0, p + BH_OFF + w * 1024);
        gload16(Blo + brow0, p + BL_OFF + w * 1024);
        gload16(Bhi + brow1, p + BH_OFF + w * 1024 + 512);
        gload16(Blo + brow1, p + BL_OFF + w * 1024 + 512);
    }

    for (int t = 0; t < nk; ++t) {
        __syncthreads();   // drains staged loads for tile t (vmcnt 0) + wave sync
        if (t + 1 < nk) {  // stage tile t+1 into the other buffer (flies under MFMA)
            int k0 = (t + 1) << 5;
            short* p = &lds[((t + 1) & 1) * BUF_SZ];
            gload16(Ahi + arow + k0, p + AH_OFF + w * 512);
            gload16(Alo + arow + k0, p + AL_OFF + w * 512);
            gload16(Bhi + brow0 + k0, p + BH_OFF + w * 1024);
            gload16(Blo + brow0 + k0, p + BL_OFF + w * 1024);
            gload16(Bhi + brow1 + k0, p + BH_OFF + w * 1024 + 512);
            gload16(Blo + brow1 + k0, p + BL_OFF + w * 1024 + 512);
        }
        const short* base = &lds[(t & 1) * BUF_SZ];

        s16x8 ah[2], al[2], bh[4], bl[4];
        #pragma unroll
        for (int g = 0; g < 2; ++g) {
            int r = wr * 32 + g * 16 + fm;
            ah[g] = *(const s16x8*)&base[AH_OFF + r * 32 + kg * 8];
            al[g] = *(const s16x8*)&base[AL_OFF + r * 32 + kg * 8];
        }
        #pragma unroll
        for (int h = 0; h < 4; ++h) {
            int c = wc * 64 + h * 16 + fm;
            bh[h] = *(const s16x8*)&base[BH_OFF + c * 32 + kg * 8];
            bl[h] = *(const s16x8*)&base[BL_OFF + c * 32 + kg * 8];
        }
        #pragma unroll
        for (int g = 0; g < 2; ++g)
            #pragma unroll
            for (int h = 0; h < 4; ++h) {
                acc[g][h] = __builtin_amdgcn_mfma_f32_16x16x32_bf16(ah[g], bh[h], acc[g][h], 0, 0, 0);
                acc[g][h] = __builtin_amdgcn_mfma_f32_16x16x32_bf16(ah[g], bl[h], acc[g][h], 0, 0, 0);
                acc[g][h] = __builtin_amdgcn_mfma_f32_16x16x32_bf16(al[g], bh[h], acc[g][h], 0, 0, 0);
            }
    }

    // epilogue: C row = kg*4 + j (within frag), col = fm
    #pragma unroll
    for (int g = 0; g < 2; ++g) {
        #pragma unroll
        for (int h = 0; h < 4; ++h) {
            #pragma unroll
            for (int j = 0; j < 4; ++j) {
                int m = m0 + wr * 32 + g * 16 + kg * 4 + j;
                int n = n0 + wc * 64 + h * 16 + fm;
                float v = acc[g][h][j];
                if (EPI == 0) {
                    if (n < DS) Out[(size_t)m * DS + n] = v;
                } else if (EPI == 2) {
                    if (n < DD) {
                        size_t o = (size_t)m * NG + n;
                        float grad = v - XD[o];
                        float yold = bf2f(Yhi[o]) + bf2f(Ylo[o]);
                        float zold = bf2f(Zhi[o]) + bf2f(Zlo[o]);
                        float gs = yold - grad * invL;
                        float az = fabsf(gs) - thr;
                        float zn = (az > 0.0f) ? copysignf(az, gs) : 0.0f;
                        float yn = zn + mom * (zn - zold);
                        __hip_bfloat16 zh = __float2bfloat16(zn);
                        Zhi[o] = zh;
                        Zlo[o] = __float2bfloat16(zn - bf2f(zh));
                        __hip_bfloat16 yh = __float2bfloat16(yn);
                        Rhi[o] = yh;
                        Rlo[o] = __float2bfloat16(yn - bf2f(yh));
                    }
                } else if (EPI == 3) {
                    Out[(size_t)m * NG + n] = v;
                } else {  // EPI == 4: split write (G)
                    size_t o = (size_t)m * NG + n;
                    __hip_bfloat16 hb = __float2bfloat16(v);
                    Rhi[o] = hb;
                    Rlo[o] = __float2bfloat16(v - bf2f(hb));
                }
            }
        }
    }
}

// ---------------------------------------------------------------------------
// Launch
// ---------------------------------------------------------------------------
extern "C" void kernel_launch(void* const* d_in, const int* in_sizes, int n_in,
                              void* d_out, int out_size, void* d_ws, size_t ws_size,
                              hipStream_t stream) {
    const float* x = (const float*)d_in[0];   // (2048, 1200)
    const float* D = (const float*)d_in[1];   // (1200, 2400)
    float* out = (float*)d_out;               // (2048, 1200)

    char* wsb = (char*)d_ws;
    float* w0 = (float*)wsb;                  // 2432
    float* w1 = w0 + 2432;                    // 2432
    float* part = w1 + 2432;                  // 21*150 = 3150
    float* scal = part + 3200;                // 3

    // persistent region
    char* p = wsb + 65536;
    __hip_bfloat16* Dhi = (__hip_bfloat16*)p;  p += (size_t)NP1 * NG * 2;
    __hip_bfloat16* Dlo = (__hip_bfloat16*)p;  p += (size_t)NP1 * NG * 2;
    __hip_bfloat16* Dthi = (__hip_bfloat16*)p; p += (size_t)NG * KP * 2;
    __hip_bfloat16* Dtlo = (__hip_bfloat16*)p; p += (size_t)NG * KP * 2;
    __hip_bfloat16* Ghi = (__hip_bfloat16*)p;  p += (size_t)NG * NG * 2;
    __hip_bfloat16* Glo = (__hip_bfloat16*)p;  p += (size_t)NG * NG * 2;
    float* XD = (float*)p;                     p += (size_t)MR * NG * 4;
    // overlay region: Xhi/Xlo live only until the XD GEMM; then Y/Z state.
    char* ov = p;
    __hip_bfloat16* Xhi = (__hip_bfloat16*)ov;
    __hip_bfloat16* Xlo = Xhi + (size_t)MR * KP;
    __hip_bfloat16* Y0hi = (__hip_bfloat16*)ov;          // zeroed after XD GEMM
    __hip_bfloat16* Y0lo = Y0hi + (size_t)MR * NG;
    __hip_bfloat16* Y1hi = Y0lo + (size_t)MR * NG;
    __hip_bfloat16* Y1lo = Y1hi + (size_t)MR * NG;
    __hip_bfloat16* Zhi = Y1lo + (size_t)MR * NG;
    __hip_bfloat16* Zlo = Zhi + (size_t)MR * NG;

    // ---- prep: splits ----
    k_makeD<<<(NP1 * NG + 255) / 256, 256, 0, stream>>>(D, Dhi, Dlo);
    k_makeDt<<<dim3(NG / 32, KP / 32), 256, 0, stream>>>(D, Dthi, Dtlo);
    k_makeX<<<(MR * KP + 255) / 256, 256, 0, stream>>>(x, Xhi, Xlo);

    // ---- G = D^T D (split bf16 out), M=N=2432, K=1216 ----
    mfma_gemm<4><<<dim3(NG / 128, NG / 64), 256, 0, stream>>>(
        Dthi, Dtlo, KP, Dthi, Dtlo, KP, KP,
        nullptr, Ghi, Glo, nullptr, nullptr, nullptr, nullptr, nullptr, 0.0f, nullptr);

    // ---- XD = x @ D (fp32 out), M=2048, N=2432, K=1216 ----
    mfma_gemm<3><<<dim3(NG / 128, MR / 64), 256, 0, stream>>>(
        Xhi, Xlo, KP, Dthi, Dtlo, KP, KP,
        nullptr, nullptr, nullptr, nullptr, nullptr, nullptr, nullptr, nullptr, 0.0f, XD);

    // ---- power iteration on split G ----
    k_init<<<1, 256, 0, stream>>>(w0, w1, part);
    for (int j = 0; j < 20; j++) {
        const float* win = (j & 1) ? w1 : w0;
        float* wout = (j & 1) ? w0 : w1;
        k_gmv<<<PPI, 1024, 0, stream>>>(Ghi, Glo, win, part + j * PPI, wout,
                                        part + (j + 1) * PPI);
    }
    k_fin<<<1, 64, 0, stream>>>(part + 20 * PPI, scal);

    // ---- zero Y0,Y1,Z (hi/lo) — also overwrites dead Xhi/Xlo ----
    {
        int n8 = 6 * MR * NG / 8;
        k_zero_s<<<(n8 + 255) / 256, 256, 0, stream>>>((s16x8*)Y0hi, n8);
    }

    // ---- FISTA: one GEMM per iteration: z=soft(y - (yG - xD)/L), Y ping-pong ----
    float t = 1.0f;
    for (int i = 0; i < 16; i++) {
        float tn = 0.5f * (1.0f + sqrtf(1.0f + 4.0f * t * t));
        float mom = (t - 1.0f) / tn;
        t = tn;
        __hip_bfloat16* Ych = (i & 1) ? Y1hi : Y0hi;
        __hip_bfloat16* Ycl = (i & 1) ? Y1lo : Y0lo;
        __hip_bfloat16* Ynh = (i & 1) ? Y0hi : Y1hi;
        __hip_bfloat16* Ynl = (i & 1) ? Y0lo : Y1lo;
        mfma_gemm<2><<<dim3(NG / 128, MR / 64), 256, 0, stream>>>(
            Ych, Ycl, NG, Ghi, Glo, NG, NG,
            XD, Ynh, Ynl, Zhi, Zlo, Ych, Ycl, scal, mom, nullptr);
    }

    // ---- final recon = z @ D^T -> out (M=2048, N=1280, K=2432) ----
    mfma_gemm<0><<<dim3(NP1 / 128, MR / 64), 256, 0, stream>>>(
        Zhi, Zlo, NG, Dhi, Dlo, NG, NG,
        nullptr, nullptr, nullptr, nullptr, nullptr, nullptr, nullptr, nullptr, 0.0f, out);
}

// Round 5
// 954.920 us; speedup vs baseline: 11.5088x; 2.8018x over previous
//
#include <hip/hip_runtime.h>
#include <hip/hip_bf16.h>
#include <cmath>

// ---------------------------------------------------------------------------
// Sizes
// ---------------------------------------------------------------------------
#define DS 1200     // signal dim
#define DD 2400     // dict dim
#define MR 2048     // rows (B*N)
#define KP 1216     // padded signal dim (38*32)
#define NP1 1280    // padded signal dim for recon B panel (10*128)
#define NG 2432     // padded dict dim (19*128)
#define PPI 150     // norm partials per power iteration

typedef __attribute__((ext_vector_type(8))) short s16x8;
typedef __attribute__((ext_vector_type(4))) float f32x4;

__device__ __forceinline__ float s2f(short s) {
    union { unsigned u; float f; } c;
    c.u = ((unsigned)(unsigned short)s) << 16;
    return c.f;
}
__device__ __forceinline__ short f2s(float f) {
    __hip_bfloat16 h = __float2bfloat16(f);
    return *reinterpret_cast<short*>(&h);
}
__device__ __forceinline__ float bf2f(__hip_bfloat16 h) { return __bfloat162float(h); }

// Packed layout: 128-row x 8-col tiles of 1024 elems, tiles ordered col-fastest
// within each 128-row block:  poff(m,n,C) = m0*C + (n>>3)*1024 + (m&127)*8 + (n&7)
// where m0 = m & ~127.

// ---------------------------------------------------------------------------
// JAX threefry2x32 + XLA f32 erfinv (reproduce jax.random.normal(key(42)))
// ---------------------------------------------------------------------------
__device__ __forceinline__ unsigned rotl32(unsigned x, int d) {
    return (x << d) | (x >> (32 - d));
}

__device__ void threefry2x32(unsigned k0, unsigned k1, unsigned x0, unsigned x1,
                             unsigned* o0, unsigned* o1) {
    unsigned ks0 = k0, ks1 = k1, ks2 = k0 ^ k1 ^ 0x1BD11BDAu;
    const int rotA[4] = {13, 15, 26, 6};
    const int rotB[4] = {17, 29, 16, 24};
    x0 += ks0; x1 += ks1;
    #pragma unroll
    for (int r = 0; r < 4; r++) { x0 += x1; x1 = rotl32(x1, rotA[r]); x1 ^= x0; }
    x0 += ks1; x1 += ks2 + 1u;
    #pragma unroll
    for (int r = 0; r < 4; r++) { x0 += x1; x1 = rotl32(x1, rotB[r]); x1 ^= x0; }
    x0 += ks2; x1 += ks0 + 2u;
    #pragma unroll
    for (int r = 0; r < 4; r++) { x0 += x1; x1 = rotl32(x1, rotA[r]); x1 ^= x0; }
    x0 += ks0; x1 += ks1 + 3u;
    #pragma unroll
    for (int r = 0; r < 4; r++) { x0 += x1; x1 = rotl32(x1, rotB[r]); x1 ^= x0; }
    x0 += ks1; x1 += ks2 + 4u;
    #pragma unroll
    for (int r = 0; r < 4; r++) { x0 += x1; x1 = rotl32(x1, rotA[r]); x1 ^= x0; }
    x0 += ks2; x1 += ks0 + 5u;
    *o0 = x0; *o1 = x1;
}

__device__ float erfinv_f32(float x) {
    float w = -logf((1.0f - x) * (1.0f + x));
    float p;
    if (w < 5.0f) {
        w -= 2.5f;
        p = 2.81022636e-08f;
        p = fmaf(p, w, 3.43273939e-07f);
        p = fmaf(p, w, -3.5233877e-06f);
        p = fmaf(p, w, -4.39150654e-06f);
        p = fmaf(p, w, 0.00021858087f);
        p = fmaf(p, w, -0.00125372503f);
        p = fmaf(p, w, -0.00417768164f);
        p = fmaf(p, w, 0.246640727f);
        p = fmaf(p, w, 1.50140941f);
    } else {
        w = sqrtf(w) - 3.0f;
        p = -0.000200214257f;
        p = fmaf(p, w, 0.000100950558f);
        p = fmaf(p, w, 0.00134934322f);
        p = fmaf(p, w, -0.00367342844f);
        p = fmaf(p, w, 0.00573950773f);
        p = fmaf(p, w, -0.0076224613f);
        p = fmaf(p, w, 0.00943887047f);
        p = fmaf(p, w, 1.00167406f);
        p = fmaf(p, w, 2.83297682f);
    }
    return p * x;
}

__device__ float bits_to_normal(unsigned bits) {
    unsigned fb = (bits >> 9) | 0x3F800000u;
    float u01 = __uint_as_float(fb) - 1.0f;
    const float lo = -0.99999994f;
    float u = u01 * 2.0f + lo;
    u = fmaxf(lo, u);
    return 1.41421356237f * erfinv_f32(u);
}

// ---------------------------------------------------------------------------
// Power iteration pieces
// ---------------------------------------------------------------------------
__global__ void k_init(float* __restrict__ w0, float* __restrict__ w1,
                       float* __restrict__ part) {
    int tid = threadIdx.x;
    for (int i = tid; i < 21 * PPI; i += 256) part[i] = 0.0f;
    if (tid < 32) {
        w0[2400 + tid] = 0.0f;
        w1[2400 + tid] = 0.0f;
    }
    __shared__ float red[256];
    float local2 = 0.0f;
    for (int p = tid; p < DS; p += 256) {
        unsigned r0, r1;
        threefry2x32(0u, 42u, (unsigned)p, (unsigned)(DS + p), &r0, &r1);
        float n0 = bits_to_normal(r0);
        float n1 = bits_to_normal(r1);
        w0[p] = n0;
        w0[DS + p] = n1;
        local2 += n0 * n0 + n1 * n1;
    }
    red[tid] = local2;
    __syncthreads();
    for (int s = 128; s > 0; s >>= 1) {
        if (tid < s) red[tid] += red[tid + s];
        __syncthreads();
    }
    if (tid == 0) part[0] = red[0];
}

// wout = Grm @ (win * rsqrt(sum partin)); partout[b] = block partial ||wout||^2
__global__ __launch_bounds__(1024) void k_gmv(const short* __restrict__ Grm,
                                              const float* __restrict__ win,
                                              const float* __restrict__ partin,
                                              float* __restrict__ wout,
                                              float* __restrict__ partout) {
    float s2 = 0.0f;
    for (int i = 0; i < PPI; i++) s2 += partin[i];
    float rn = 1.0f / sqrtf(s2);
    int wave = threadIdx.x >> 6, lane = threadIdx.x & 63;
    int row = blockIdx.x * 16 + wave;       // 150 * 16 = 2400 rows
    const s16x8* gh = (const s16x8*)(Grm + (size_t)row * NG);
    const float4* w4 = (const float4*)win;
    float acc = 0.0f;
    #pragma unroll
    for (int i = 0; i < 5; i++) {
        int c = lane + i * 64;              // 304 chunks
        if (c < 304) {
            s16x8 h = gh[c];
            float4 wa = w4[c * 2], wb = w4[c * 2 + 1];
            acc += s2f(h[0]) * wa.x + s2f(h[1]) * wa.y;
            acc += s2f(h[2]) * wa.z + s2f(h[3]) * wa.w;
            acc += s2f(h[4]) * wb.x + s2f(h[5]) * wb.y;
            acc += s2f(h[6]) * wb.z + s2f(h[7]) * wb.w;
        }
    }
    #pragma unroll
    for (int off = 32; off > 0; off >>= 1) acc += __shfl_xor(acc, off, 64);
    __shared__ float red[16];
    if (lane == 0) {
        float val = acc * rn;
        wout[row] = val;
        red[wave] = val * val;
    }
    __syncthreads();
    if (threadIdx.x == 0) {
        float s = 0.0f;
        #pragma unroll
        for (int i = 0; i < 16; i++) s += red[i];
        partout[blockIdx.x] = s;
    }
}

__global__ void k_fin(const float* __restrict__ part20, float* __restrict__ scal) {
    if (threadIdx.x == 0) {
        float s = 0.0f;
        for (int i = 0; i < PPI; i++) s += part20[i];
        float L = sqrtf(s);
        scal[0] = L;
        scal[1] = 1.0f / L;
        scal[2] = 0.1f / L;
    }
}

// ---------------------------------------------------------------------------
// Prep kernels (write packed layouts)
// ---------------------------------------------------------------------------
// Dp: recon B panel, rows = signal d (1280), cols = dict k (2432), single bf16
__global__ void k_makeD(const float* __restrict__ D, short* __restrict__ Dp) {
    int p = blockIdx.x * 256 + threadIdx.x;     // NP1*NG
    if (p >= NP1 * NG) return;
    int tile = p >> 10, win = p & 1023;
    int row = win >> 3, e = win & 7;
    int mt = tile / (NG >> 3), ct = tile % (NG >> 3);
    int d = mt * 128 + row, n = ct * 8 + e;
    float v = (d < DS && n < DD) ? D[(size_t)d * DD + n] : 0.0f;
    Dp[p] = f2s(v);
}

// Xp: XD-GEMM A operand, rows m (2048), cols k (1216), split
__global__ void k_makeX(const float* __restrict__ x,
                        short* __restrict__ Xhi, short* __restrict__ Xlo) {
    int p = blockIdx.x * 256 + threadIdx.x;     // MR*KP
    if (p >= MR * KP) return;
    int tile = p >> 10, win = p & 1023;
    int row = win >> 3, e = win & 7;
    int mt = tile / (KP >> 3), ct = tile % (KP >> 3);
    int m = mt * 128 + row, k = ct * 8 + e;
    float v = (k < DS) ? x[(size_t)m * DS + k] : 0.0f;
    short h = f2s(v);
    Xhi[p] = h;
    Xlo[p] = f2s(v - s2f(h));
}

// Dtp: rows = dict col c (2432), cols = signal k (1216), split, packed
__global__ void k_makeDt(const float* __restrict__ D,
                         short* __restrict__ Dthi, short* __restrict__ Dtlo) {
    __shared__ float t[32][33];
    int bc = blockIdx.x * 32;   // dict base (0..2431)
    int bk = blockIdx.y * 32;   // signal base (0..1215)
    int tx = threadIdx.x & 31, ty = threadIdx.x >> 5;
    for (int i = ty; i < 32; i += 8) {
        int k = bk + i, c = bc + tx;
        t[i][tx] = (k < DS && c < DD) ? D[(size_t)k * DD + c] : 0.0f;
    }
    __syncthreads();
    for (int i = ty; i < 32; i += 8) {
        int c = bc + i, k = bk + tx;
        float v = t[tx][i];
        short h = f2s(v);
        size_t po = ((size_t)(c >> 7) * (KP >> 3) + (k >> 3)) * 1024 +
                    ((c & 127) << 3) + (k & 7);
        Dthi[po] = h;
        Dtlo[po] = f2s(v - s2f(h));
    }
}

__global__ void k_zero_s(s16x8* __restrict__ p, int n8) {
    int i = blockIdx.x * blockDim.x + threadIdx.x;
    if (i < n8) {
        s16x8 z = {0, 0, 0, 0, 0, 0, 0, 0};
        p[i] = z;
    }
}

// ---------------------------------------------------------------------------
// MFMA GEMM on packed operands. Tile 128x128, 4 waves (each 64x64).
// SPLIT: BK=32, 3-MFMA hi/lo split.  non-SPLIT: BK=64, single bf16.
//   out[m][n] = sum_k A[m][k] * B[n][k]
// EPI 0: Out[m*DS+n] = acc (n<DS)                  (final recon)
// EPI 2: FISTA: grad=acc-XD; gs=yold-grad/L; z=soft(gs); ynext=z+mom(z-zold)
// EPI 3: Out[m*NG+n] = acc fp32                    (XD precompute)
// EPI 4: Gp[poff]=bf16(acc); Grm[m*NG+n]=bf16(acc) (G precompute)
// ---------------------------------------------------------------------------
__device__ __forceinline__ void gload16(const void* g, void* l) {
    __builtin_amdgcn_global_load_lds(
        (const __attribute__((address_space(1))) unsigned int*)g,
        (__attribute__((address_space(3))) unsigned int*)l, 16, 0, 0);
}

template <int EPI, bool SPLIT>
__global__ __launch_bounds__(256) void mfma_gemm(
    const short* __restrict__ Ah, const short* __restrict__ Al, int CA,
    const short* __restrict__ Bh, const short* __restrict__ Bl, int CB,
    int K, int swz,
    const float* __restrict__ XDc, const float* __restrict__ scal, float mom,
    short* __restrict__ Ynew, short* __restrict__ Zst,
    short* __restrict__ Gp, short* __restrict__ Grm,
    float* __restrict__ Out) {
    constexpr int BK = SPLIT ? 32 : 64;
    constexpr int ASZ = 128 * BK;            // shorts per operand array in LDS
    constexpr int RNDS = (128 * (BK / 8)) / 256;   // staging rounds: 2 or 4
    constexpr int ALO_ = SPLIT ? ASZ : 0;
    constexpr int BHO_ = SPLIT ? 2 * ASZ : ASZ;
    constexpr int BLO_ = 3 * ASZ;
    __shared__ __align__(16) short lds[2 * 16384];   // 64 KB, double buffered

    const int tid = threadIdx.x;
    const int w = tid >> 6, lane = tid & 63;
    const int fm = lane & 15, kg = lane >> 4;
    const int wr = w >> 1, wc = w & 1;       // wave -> 64x64 quadrant

    int bx, by;
    if (swz) {
        int q = gridDim.x >> 3;              // grid divisible by 8
        int s = (blockIdx.x & 7) * q + (blockIdx.x >> 3);
        bx = s >> 4; by = s & 15;            // 16 M-blocks always
    } else { bx = blockIdx.x; by = blockIdx.y; }
    const int m0 = by * 128, n0 = bx * 128;

    f32x4 acc[4][4];
    #pragma unroll
    for (int g = 0; g < 4; ++g)
        #pragma unroll
        for (int h = 0; h < 4; ++h) acc[g][h] = f32x4{0.f, 0.f, 0.f, 0.f};

    float invL = 0.0f, thr = 0.0f;
    if (EPI == 2) { invL = scal[1]; thr = scal[2]; }

    // per-thread staging source offset (packed layout)
    const int soff0 = ((tid >> 7) << 10) + ((tid & 127) << 3);
    const size_t Abase = (size_t)m0 * CA + soff0;
    const size_t Bbase = (size_t)n0 * CB + soff0;

    const int nk = K / BK;

    auto STAGE = [&](int t, int cur) {
        const int kk = t * (BK * 128 / 8) * 8;   // = t*BK*128 elems
        short* bp = &lds[cur * 16384];
        #pragma unroll
        for (int r = 0; r < RNDS; ++r) {
            const int lo = (r * 256 + w * 64) * 8;
            gload16(Ah + Abase + kk + r * 2048, bp + lo);
            if constexpr (SPLIT) gload16(Al + Abase + kk + r * 2048, bp + ALO_ + lo);
            gload16(Bh + Bbase + kk + r * 2048, bp + BHO_ + lo);
            if constexpr (SPLIT) gload16(Bl + Bbase + kk + r * 2048, bp + BLO_ + lo);
        }
    };

    STAGE(0, 0);

    for (int t = 0; t < nk; ++t) {
        __syncthreads();                       // drains staged loads for tile t
        if (t + 1 < nk) STAGE(t + 1, (t + 1) & 1);
        const short* bs = &lds[(t & 1) * 16384];

        #pragma unroll
        for (int ks = 0; ks < BK / 32; ++ks) {
            const int c = ks * 4 + kg;
            s16x8 a[4], b[4];
            #pragma unroll
            for (int g = 0; g < 4; ++g)
                a[g] = *(const s16x8*)&bs[c * 1024 + (wr * 64 + g * 16 + fm) * 8];
            #pragma unroll
            for (int h = 0; h < 4; ++h)
                b[h] = *(const s16x8*)&bs[BHO_ + c * 1024 + (wc * 64 + h * 16 + fm) * 8];
            if constexpr (SPLIT) {
                s16x8 a2[4], b2[4];
                #pragma unroll
                for (int g = 0; g < 4; ++g)
                    a2[g] = *(const s16x8*)&bs[ALO_ + c * 1024 + (wr * 64 + g * 16 + fm) * 8];
                #pragma unroll
                for (int h = 0; h < 4; ++h)
                    b2[h] = *(const s16x8*)&bs[BLO_ + c * 1024 + (wc * 64 + h * 16 + fm) * 8];
                #pragma unroll
                for (int g = 0; g < 4; ++g)
                    #pragma unroll
                    for (int h = 0; h < 4; ++h) {
                        acc[g][h] = __builtin_amdgcn_mfma_f32_16x16x32_bf16(a[g], b[h], acc[g][h], 0, 0, 0);
                        acc[g][h] = __builtin_amdgcn_mfma_f32_16x16x32_bf16(a[g], b2[h], acc[g][h], 0, 0, 0);
                        acc[g][h] = __builtin_amdgcn_mfma_f32_16x16x32_bf16(a2[g], b[h], acc[g][h], 0, 0, 0);
                    }
            } else {
                #pragma unroll
                for (int g = 0; g < 4; ++g)
                    #pragma unroll
                    for (int h = 0; h < 4; ++h)
                        acc[g][h] = __builtin_amdgcn_mfma_f32_16x16x32_bf16(a[g], b[h], acc[g][h], 0, 0, 0);
            }
        }
    }

    // epilogue: frag (row = kg*4+j, col = fm)
    #pragma unroll
    for (int g = 0; g < 4; ++g) {
        #pragma unroll
        for (int h = 0; h < 4; ++h) {
            #pragma unroll
            for (int j = 0; j < 4; ++j) {
                int m = m0 + wr * 64 + g * 16 + kg * 4 + j;
                int n = n0 + wc * 64 + h * 16 + fm;
                float v = acc[g][h][j];
                if (EPI == 0) {
                    if (n < DS) Out[(size_t)m * DS + n] = v;
                } else if (EPI == 2) {
                    size_t o = (size_t)m * NG + n;
                    size_t pz = (size_t)(m & ~127) * NG + ((n >> 3) << 10) +
                                ((m & 127) << 3) + (n & 7);
                    float grad = v - XDc[o];
                    float yold = s2f(Ah[pz]);
                    float zold = s2f(Zst[pz]);
                    float gs = yold - grad * invL;
                    float az = fabsf(gs) - thr;
                    float zn = (az > 0.0f) ? copysignf(az, gs) : 0.0f;
                    float yn = zn + mom * (zn - zold);
                    Zst[pz] = f2s(zn);
                    Ynew[pz] = f2s(yn);
                } else if (EPI == 3) {
                    Out[(size_t)m * NG + n] = v;
                } else {  // EPI == 4
                    size_t pz = (size_t)(m & ~127) * NG + ((n >> 3) << 10) +
                                ((m & 127) << 3) + (n & 7);
                    short hv = f2s(v);
                    Gp[pz] = hv;
                    Grm[(size_t)m * NG + n] = hv;
                }
            }
        }
    }
}

// ---------------------------------------------------------------------------
// Launch
// ---------------------------------------------------------------------------
extern "C" void kernel_launch(void* const* d_in, const int* in_sizes, int n_in,
                              void* d_out, int out_size, void* d_ws, size_t ws_size,
                              hipStream_t stream) {
    const float* x = (const float*)d_in[0];   // (2048, 1200)
    const float* D = (const float*)d_in[1];   // (1200, 2400)
    float* out = (float*)d_out;               // (2048, 1200)

    char* wsb = (char*)d_ws;
    float* w0 = (float*)wsb;                  // 2432
    float* w1 = w0 + 2432;
    float* part = w1 + 2432;                  // 21*150
    float* scal = part + 3200;                // 3

    char* p = wsb + 65536;
    short* Dp   = (short*)p; p += (size_t)NP1 * NG * 2;    // 6.2 MB
    short* Dthi = (short*)p; p += (size_t)NG * KP * 2;     // 5.9 MB
    short* Dtlo = (short*)p; p += (size_t)NG * KP * 2;
    short* Xhi  = (short*)p; p += (size_t)MR * KP * 2;     // 5.0 MB
    short* Xlo  = (short*)p; p += (size_t)MR * KP * 2;
    short* Gp   = (short*)p; p += (size_t)NG * NG * 2;     // 11.8 MB
    short* Grm  = (short*)p; p += (size_t)NG * NG * 2;     // 11.8 MB
    float* XD   = (float*)p; p += (size_t)MR * NG * 4;     // 19.9 MB
    short* Y0p  = (short*)p; p += (size_t)MR * NG * 2;     // 10 MB (zeroed)
    short* Zp   = (short*)p; p += (size_t)MR * NG * 2;     // 10 MB (zeroed, adj)
    short* Y1p  = (short*)p; p += (size_t)MR * NG * 2;     // 10 MB

    // ---- prep ----
    k_makeD<<<(NP1 * NG + 255) / 256, 256, 0, stream>>>(D, Dp);
    k_makeDt<<<dim3(NG / 32, KP / 32), 256, 0, stream>>>(D, Dthi, Dtlo);
    k_makeX<<<(MR * KP + 255) / 256, 256, 0, stream>>>(x, Xhi, Xlo);

    // ---- G = D^T D (split, high precision) -> Gp packed bf16 + Grm row-major
    mfma_gemm<4, true><<<dim3(NG / 128, NG / 128), 256, 0, stream>>>(
        Dthi, Dtlo, KP, Dthi, Dtlo, KP, KP, 0,
        nullptr, nullptr, 0.0f, nullptr, nullptr, Gp, Grm, nullptr);

    // ---- XD = x @ D (split) -> fp32, row-major stride NG
    mfma_gemm<3, true><<<dim3(304), 256, 0, stream>>>(
        Xhi, Xlo, KP, Dthi, Dtlo, KP, KP, 1,
        nullptr, nullptr, 0.0f, nullptr, nullptr, nullptr, nullptr, XD);

    // ---- power iteration on Grm ----
    k_init<<<1, 256, 0, stream>>>(w0, w1, part);
    for (int j = 0; j < 20; j++) {
        const float* win = (j & 1) ? w1 : w0;
        float* wout = (j & 1) ? w0 : w1;
        k_gmv<<<PPI, 1024, 0, stream>>>(Grm, win, part + j * PPI, wout,
                                        part + (j + 1) * PPI);
    }
    k_fin<<<1, 64, 0, stream>>>(part + 20 * PPI, scal);

    // ---- zero Y0, Z (adjacent) ----
    {
        int n8 = 2 * MR * NG / 8;
        k_zero_s<<<(n8 + 255) / 256, 256, 0, stream>>>((s16x8*)Y0p, n8);
    }

    // ---- FISTA: z = soft(y - (yG - xD)/L); y ping-pong ----
    float t = 1.0f;
    for (int i = 0; i < 16; i++) {
        float tn = 0.5f * (1.0f + sqrtf(1.0f + 4.0f * t * t));
        float mom = (t - 1.0f) / tn;
        t = tn;
        short* Yc = (i & 1) ? Y1p : Y0p;
        short* Yn = (i & 1) ? Y0p : Y1p;
        mfma_gemm<2, false><<<dim3(304), 256, 0, stream>>>(
            Yc, nullptr, NG, Gp, nullptr, NG, NG, 1,
            XD, scal, mom, Yn, Zp, nullptr, nullptr, nullptr);
    }

    // ---- final recon = z @ D^T -> out ----
    mfma_gemm<0, false><<<dim3(160), 256, 0, stream>>>(
        Zp, nullptr, NG, Dp, nullptr, NG, NG, 1,
        nullptr, nullptr, 0.0f, nullptr, nullptr, nullptr, nullptr, out);
}

// Round 6
// 940.492 us; speedup vs baseline: 11.6854x; 1.0153x over previous
//
#include <hip/hip_runtime.h>
#include <hip/hip_bf16.h>
#include <cmath>

// ---------------------------------------------------------------------------
// Sizes
// ---------------------------------------------------------------------------
#define DS 1200     // signal dim
#define DD 2400     // dict dim
#define MR 2048     // rows (B*N)
#define KP 1216     // padded signal dim (38*32)
#define NP1 1280    // padded signal dim for recon B panel (10*128)
#define NG 2432     // padded dict dim (19*128)
#define PPI 150     // norm partials per power iteration

typedef __attribute__((ext_vector_type(8))) short s16x8;
typedef __attribute__((ext_vector_type(4))) float f32x4;

__device__ __forceinline__ float s2f(short s) {
    union { unsigned u; float f; } c;
    c.u = ((unsigned)(unsigned short)s) << 16;
    return c.f;
}
__device__ __forceinline__ short f2s(float f) {
    __hip_bfloat16 h = __float2bfloat16(f);
    return *reinterpret_cast<short*>(&h);
}

// Packed layout: 128-row bands; within a band, 8-col k-subtiles of 1024 elems:
//   poff(m,k,C) = (m&~127)*C + (k>>3)*1024 + (m&127)*8 + (k&7)

// ---------------------------------------------------------------------------
// JAX threefry2x32 + XLA f32 erfinv (reproduce jax.random.normal(key(42)))
// ---------------------------------------------------------------------------
__device__ __forceinline__ unsigned rotl32(unsigned x, int d) {
    return (x << d) | (x >> (32 - d));
}

__device__ void threefry2x32(unsigned k0, unsigned k1, unsigned x0, unsigned x1,
                             unsigned* o0, unsigned* o1) {
    unsigned ks0 = k0, ks1 = k1, ks2 = k0 ^ k1 ^ 0x1BD11BDAu;
    const int rotA[4] = {13, 15, 26, 6};
    const int rotB[4] = {17, 29, 16, 24};
    x0 += ks0; x1 += ks1;
    #pragma unroll
    for (int r = 0; r < 4; r++) { x0 += x1; x1 = rotl32(x1, rotA[r]); x1 ^= x0; }
    x0 += ks1; x1 += ks2 + 1u;
    #pragma unroll
    for (int r = 0; r < 4; r++) { x0 += x1; x1 = rotl32(x1, rotB[r]); x1 ^= x0; }
    x0 += ks2; x1 += ks0 + 2u;
    #pragma unroll
    for (int r = 0; r < 4; r++) { x0 += x1; x1 = rotl32(x1, rotA[r]); x1 ^= x0; }
    x0 += ks0; x1 += ks1 + 3u;
    #pragma unroll
    for (int r = 0; r < 4; r++) { x0 += x1; x1 = rotl32(x1, rotB[r]); x1 ^= x0; }
    x0 += ks1; x1 += ks2 + 4u;
    #pragma unroll
    for (int r = 0; r < 4; r++) { x0 += x1; x1 = rotl32(x1, rotA[r]); x1 ^= x0; }
    x0 += ks2; x1 += ks0 + 5u;
    *o0 = x0; *o1 = x1;
}

__device__ float erfinv_f32(float x) {
    float w = -logf((1.0f - x) * (1.0f + x));
    float p;
    if (w < 5.0f) {
        w -= 2.5f;
        p = 2.81022636e-08f;
        p = fmaf(p, w, 3.43273939e-07f);
        p = fmaf(p, w, -3.5233877e-06f);
        p = fmaf(p, w, -4.39150654e-06f);
        p = fmaf(p, w, 0.00021858087f);
        p = fmaf(p, w, -0.00125372503f);
        p = fmaf(p, w, -0.00417768164f);
        p = fmaf(p, w, 0.246640727f);
        p = fmaf(p, w, 1.50140941f);
    } else {
        w = sqrtf(w) - 3.0f;
        p = -0.000200214257f;
        p = fmaf(p, w, 0.000100950558f);
        p = fmaf(p, w, 0.00134934322f);
        p = fmaf(p, w, -0.00367342844f);
        p = fmaf(p, w, 0.00573950773f);
        p = fmaf(p, w, -0.0076224613f);
        p = fmaf(p, w, 0.00943887047f);
        p = fmaf(p, w, 1.00167406f);
        p = fmaf(p, w, 2.83297682f);
    }
    return p * x;
}

__device__ float bits_to_normal(unsigned bits) {
    unsigned fb = (bits >> 9) | 0x3F800000u;
    float u01 = __uint_as_float(fb) - 1.0f;
    const float lo = -0.99999994f;
    float u = u01 * 2.0f + lo;
    u = fmaxf(lo, u);
    return 1.41421356237f * erfinv_f32(u);
}

// ---------------------------------------------------------------------------
// Power iteration pieces
// ---------------------------------------------------------------------------
__global__ void k_init(float* __restrict__ w0, float* __restrict__ w1,
                       float* __restrict__ part) {
    int tid = threadIdx.x;
    for (int i = tid; i < 21 * PPI; i += 256) part[i] = 0.0f;
    if (tid < 32) {
        w0[2400 + tid] = 0.0f;
        w1[2400 + tid] = 0.0f;
    }
    __shared__ float red[256];
    float local2 = 0.0f;
    for (int p = tid; p < DS; p += 256) {
        unsigned r0, r1;
        threefry2x32(0u, 42u, (unsigned)p, (unsigned)(DS + p), &r0, &r1);
        float n0 = bits_to_normal(r0);
        float n1 = bits_to_normal(r1);
        w0[p] = n0;
        w0[DS + p] = n1;
        local2 += n0 * n0 + n1 * n1;
    }
    red[tid] = local2;
    __syncthreads();
    for (int s = 128; s > 0; s >>= 1) {
        if (tid < s) red[tid] += red[tid + s];
        __syncthreads();
    }
    if (tid == 0) part[0] = red[0];
}

__global__ __launch_bounds__(1024) void k_gmv(const short* __restrict__ Grm,
                                              const float* __restrict__ win,
                                              const float* __restrict__ partin,
                                              float* __restrict__ wout,
                                              float* __restrict__ partout) {
    float s2 = 0.0f;
    for (int i = 0; i < PPI; i++) s2 += partin[i];
    float rn = 1.0f / sqrtf(s2);
    int wave = threadIdx.x >> 6, lane = threadIdx.x & 63;
    int row = blockIdx.x * 16 + wave;       // 150 * 16 = 2400 rows
    const s16x8* gh = (const s16x8*)(Grm + (size_t)row * NG);
    const float4* w4 = (const float4*)win;
    float acc = 0.0f;
    #pragma unroll
    for (int i = 0; i < 5; i++) {
        int c = lane + i * 64;              // 304 chunks
        if (c < 304) {
            s16x8 h = gh[c];
            float4 wa = w4[c * 2], wb = w4[c * 2 + 1];
            acc += s2f(h[0]) * wa.x + s2f(h[1]) * wa.y;
            acc += s2f(h[2]) * wa.z + s2f(h[3]) * wa.w;
            acc += s2f(h[4]) * wb.x + s2f(h[5]) * wb.y;
            acc += s2f(h[6]) * wb.z + s2f(h[7]) * wb.w;
        }
    }
    #pragma unroll
    for (int off = 32; off > 0; off >>= 1) acc += __shfl_xor(acc, off, 64);
    __shared__ float red[16];
    if (lane == 0) {
        float val = acc * rn;
        wout[row] = val;
        red[wave] = val * val;
    }
    __syncthreads();
    if (threadIdx.x == 0) {
        float s = 0.0f;
        #pragma unroll
        for (int i = 0; i < 16; i++) s += red[i];
        partout[blockIdx.x] = s;
    }
}

__global__ void k_fin(const float* __restrict__ part20, float* __restrict__ scal) {
    if (threadIdx.x == 0) {
        float s = 0.0f;
        for (int i = 0; i < PPI; i++) s += part20[i];
        float L = sqrtf(s);
        scal[0] = L;
        scal[1] = 1.0f / L;
        scal[2] = 0.1f / L;
    }
}

// ---------------------------------------------------------------------------
// Prep kernels (write packed layouts)
// ---------------------------------------------------------------------------
__global__ void k_makeD(const float* __restrict__ D, short* __restrict__ Dp) {
    int p = blockIdx.x * 256 + threadIdx.x;     // NP1*NG
    if (p >= NP1 * NG) return;
    int tile = p >> 10, win = p & 1023;
    int row = win >> 3, e = win & 7;
    int mt = tile / (NG >> 3), ct = tile % (NG >> 3);
    int d = mt * 128 + row, n = ct * 8 + e;
    float v = (d < DS && n < DD) ? D[(size_t)d * DD + n] : 0.0f;
    Dp[p] = f2s(v);
}

__global__ void k_makeX(const float* __restrict__ x,
                        short* __restrict__ Xhi, short* __restrict__ Xlo) {
    int p = blockIdx.x * 256 + threadIdx.x;     // MR*KP
    if (p >= MR * KP) return;
    int tile = p >> 10, win = p & 1023;
    int row = win >> 3, e = win & 7;
    int mt = tile / (KP >> 3), ct = tile % (KP >> 3);
    int m = mt * 128 + row, k = ct * 8 + e;
    float v = (k < DS) ? x[(size_t)m * DS + k] : 0.0f;
    short h = f2s(v);
    Xhi[p] = h;
    Xlo[p] = f2s(v - s2f(h));
}

__global__ void k_makeDt(const float* __restrict__ D,
                         short* __restrict__ Dthi, short* __restrict__ Dtlo) {
    __shared__ float t[32][33];
    int bc = blockIdx.x * 32;   // dict base
    int bk = blockIdx.y * 32;   // signal base
    int tx = threadIdx.x & 31, ty = threadIdx.x >> 5;
    for (int i = ty; i < 32; i += 8) {
        int k = bk + i, c = bc + tx;
        t[i][tx] = (k < DS && c < DD) ? D[(size_t)k * DD + c] : 0.0f;
    }
    __syncthreads();
    for (int i = ty; i < 32; i += 8) {
        int c = bc + i, k = bk + tx;
        float v = t[tx][i];
        short h = f2s(v);
        size_t po = ((size_t)(c >> 7) * (KP >> 3) + (k >> 3)) * 1024 +
                    ((c & 127) << 3) + (k & 7);
        Dthi[po] = h;
        Dtlo[po] = f2s(v - s2f(h));
    }
}

// FISTA iteration 0 (y0=0): z1 = soft(XD/L, thr); y1 = z1 (mom=0).
__global__ void k_fista0(const float* __restrict__ XD, const float* __restrict__ scal,
                         short* __restrict__ Z, short* __restrict__ Y) {
    int i = blockIdx.x * 256 + threadIdx.x;      // over MR*NG/8
    if (i >= MR * NG / 8) return;
    float invL = scal[1], thr = scal[2];
    int e0 = i * 8;
    int band = e0 / (128 * NG);
    int rem = e0 - band * (128 * NG);
    int tile = rem >> 10;
    int row = (rem & 1023) >> 3;
    int m = band * 128 + row;
    int n = tile * 8;
    const float4* xp = (const float4*)(XD + (size_t)m * NG + n);
    float4 v0 = xp[0], v1 = xp[1];
    float vs[8] = {v0.x, v0.y, v0.z, v0.w, v1.x, v1.y, v1.z, v1.w};
    s16x8 zs;
    #pragma unroll
    for (int k = 0; k < 8; k++) {
        float gs = vs[k] * invL;
        float az = fabsf(gs) - thr;
        float zn = (az > 0.0f) ? copysignf(az, gs) : 0.0f;
        zs[k] = f2s(zn);
    }
    ((s16x8*)Z)[i] = zs;
    ((s16x8*)Y)[i] = zs;
}

// ---------------------------------------------------------------------------
// MFMA GEMM on packed operands. Tile 64(M) x 128(N), BK=32, 4 waves (32x64).
// SPLIT: 3-MFMA hi/lo split (high precision); else single bf16.
//   out[m][n] = sum_k A[m][k] * B[n][k]
// EPI 0: Out[m*DS+n] = acc (n<DS)                  (final recon)
// EPI 2: FISTA: grad=acc-XD; gs=yold-grad/L; z=soft(gs); ynext=z+mom(z-zold)
// EPI 3: Out[m*NG+n] = acc fp32                    (XD precompute)
// EPI 4: Gp[poff]=bf16(acc); Grm[m*NG+n]=bf16(acc) (G precompute)
// ---------------------------------------------------------------------------
__device__ __forceinline__ void gload16(const void* g, void* l) {
    __builtin_amdgcn_global_load_lds(
        (const __attribute__((address_space(1))) unsigned int*)g,
        (__attribute__((address_space(3))) unsigned int*)l, 16, 0, 0);
}

template <int EPI, bool SPLIT>
__global__ __launch_bounds__(256, 4) void mfma_gemm(
    const short* __restrict__ Ah, const short* __restrict__ Al, int CA,
    const short* __restrict__ Bh, const short* __restrict__ Bl, int CB,
    int K, int swz,
    const float* __restrict__ XDc, const float* __restrict__ scal, float mom,
    short* __restrict__ Ynew, short* __restrict__ Zst,
    short* __restrict__ Gp, short* __restrict__ Grm,
    float* __restrict__ Out) {
    constexpr int ALO = 2048;                 // shorts (A region: 4 subtiles x 512)
    constexpr int BHO = SPLIT ? 4096 : 2048;  // B region: 4 subtiles x 1024
    constexpr int BLO = 8192;
    constexpr int BUF = SPLIT ? 12288 : 6144; // shorts per buffer
    __shared__ __align__(16) short lds[2 * BUF];

    const int tid = threadIdx.x;
    const int w = tid >> 6, lane = tid & 63;
    const int fm = lane & 15, kg = lane >> 4;
    const int wr = w >> 1, wc = w & 1;        // wave -> 32x64 quadrant

    int bx, by;
    if (swz) {
        int q = gridDim.x >> 3;               // grid divisible by 8
        int s = (blockIdx.x & 7) * q + (blockIdx.x >> 3);
        by = s & 31; bx = s >> 5;             // 32 M-blocks (M=2048)
    } else { bx = blockIdx.x; by = blockIdx.y; }
    const int m0 = by * 64, n0 = bx * 128;

    f32x4 acc[2][4];
    #pragma unroll
    for (int g = 0; g < 2; ++g)
        #pragma unroll
        for (int h = 0; h < 4; ++h) acc[g][h] = f32x4{0.f, 0.f, 0.f, 0.f};

    float invL = 0.0f, thr = 0.0f;
    if (EPI == 2) { invL = scal[1]; thr = scal[2]; }

    // staging source addresses (per-lane global, wave-uniform LDS dest)
    const int half = (m0 >> 6) & 1;
    const size_t Aoff = (size_t)(m0 & ~127) * CA + w * 1024 + half * 512 + lane * 8;
    const size_t Boff = (size_t)n0 * CB + w * 512 + lane * 8;

    const int nk = K >> 5;

    auto STAGE = [&](int t, int cur) {
        const int kk = t << 12;               // t * 32 * 128 elems
        short* bp = &lds[cur * BUF];
        gload16(Ah + Aoff + kk, bp + w * 512);
        gload16(Bh + Boff + kk, bp + BHO + w * 512);
        gload16(Bh + Boff + kk + 2048, bp + BHO + 2048 + w * 512);
        if constexpr (SPLIT) {
            gload16(Al + Aoff + kk, bp + ALO + w * 512);
            gload16(Bl + Boff + kk, bp + BLO + w * 512);
            gload16(Bl + Boff + kk + 2048, bp + BLO + 2048 + w * 512);
        }
    };

    STAGE(0, 0);

    for (int t = 0; t < nk; ++t) {
        __syncthreads();                      // drains staged loads for tile t
        if (t + 1 < nk) STAGE(t + 1, (t + 1) & 1);
        const short* bs = &lds[(t & 1) * BUF];

        s16x8 a[2], b[4];
        #pragma unroll
        for (int g = 0; g < 2; ++g)
            a[g] = *(const s16x8*)&bs[kg * 512 + (wr * 32 + g * 16 + fm) * 8];
        #pragma unroll
        for (int h = 0; h < 4; ++h)
            b[h] = *(const s16x8*)&bs[BHO + kg * 1024 + (wc * 64 + h * 16 + fm) * 8];
        if constexpr (SPLIT) {
            s16x8 a2[2], b2[4];
            #pragma unroll
            for (int g = 0; g < 2; ++g)
                a2[g] = *(const s16x8*)&bs[ALO + kg * 512 + (wr * 32 + g * 16 + fm) * 8];
            #pragma unroll
            for (int h = 0; h < 4; ++h)
                b2[h] = *(const s16x8*)&bs[BLO + kg * 1024 + (wc * 64 + h * 16 + fm) * 8];
            #pragma unroll
            for (int g = 0; g < 2; ++g)
                #pragma unroll
                for (int h = 0; h < 4; ++h) {
                    acc[g][h] = __builtin_amdgcn_mfma_f32_16x16x32_bf16(a[g], b[h], acc[g][h], 0, 0, 0);
                    acc[g][h] = __builtin_amdgcn_mfma_f32_16x16x32_bf16(a[g], b2[h], acc[g][h], 0, 0, 0);
                    acc[g][h] = __builtin_amdgcn_mfma_f32_16x16x32_bf16(a2[g], b[h], acc[g][h], 0, 0, 0);
                }
        } else {
            #pragma unroll
            for (int g = 0; g < 2; ++g)
                #pragma unroll
                for (int h = 0; h < 4; ++h)
                    acc[g][h] = __builtin_amdgcn_mfma_f32_16x16x32_bf16(a[g], b[h], acc[g][h], 0, 0, 0);
        }
    }

    // epilogue: frag (row = kg*4+j, col = fm)
    #pragma unroll
    for (int g = 0; g < 2; ++g) {
        #pragma unroll
        for (int h = 0; h < 4; ++h) {
            #pragma unroll
            for (int j = 0; j < 4; ++j) {
                int m = m0 + wr * 32 + g * 16 + kg * 4 + j;
                int n = n0 + wc * 64 + h * 16 + fm;
                float v = acc[g][h][j];
                if (EPI == 0) {
                    if (n < DS) Out[(size_t)m * DS + n] = v;
                } else if (EPI == 2) {
                    size_t o = (size_t)m * NG + n;
                    size_t pz = (size_t)(m & ~127) * NG + ((n >> 3) << 10) +
                                ((m & 127) << 3) + (n & 7);
                    float grad = v - XDc[o];
                    float yold = s2f(Ah[pz]);
                    float zold = s2f(Zst[pz]);
                    float gs = yold - grad * invL;
                    float az = fabsf(gs) - thr;
                    float zn = (az > 0.0f) ? copysignf(az, gs) : 0.0f;
                    float yn = zn + mom * (zn - zold);
                    Zst[pz] = f2s(zn);
                    Ynew[pz] = f2s(yn);
                } else if (EPI == 3) {
                    Out[(size_t)m * NG + n] = v;
                } else {  // EPI == 4
                    size_t pz = (size_t)(m & ~127) * NG + ((n >> 3) << 10) +
                                ((m & 127) << 3) + (n & 7);
                    short hv = f2s(v);
                    Gp[pz] = hv;
                    Grm[(size_t)m * NG + n] = hv;
                }
            }
        }
    }
}

// ---------------------------------------------------------------------------
// Launch
// ---------------------------------------------------------------------------
extern "C" void kernel_launch(void* const* d_in, const int* in_sizes, int n_in,
                              void* d_out, int out_size, void* d_ws, size_t ws_size,
                              hipStream_t stream) {
    const float* x = (const float*)d_in[0];   // (2048, 1200)
    const float* D = (const float*)d_in[1];   // (1200, 2400)
    float* out = (float*)d_out;               // (2048, 1200)

    char* wsb = (char*)d_ws;
    float* w0 = (float*)wsb;                  // 2432
    float* w1 = w0 + 2432;
    float* part = w1 + 2432;                  // 21*150
    float* scal = part + 3200;                // 3

    char* p = wsb + 65536;
    short* Dp   = (short*)p; p += (size_t)NP1 * NG * 2;    // 6.2 MB
    short* Dthi = (short*)p; p += (size_t)NG * KP * 2;     // 5.9 MB
    short* Dtlo = (short*)p; p += (size_t)NG * KP * 2;
    short* Xhi  = (short*)p; p += (size_t)MR * KP * 2;     // 5.0 MB
    short* Xlo  = (short*)p; p += (size_t)MR * KP * 2;
    short* Gp   = (short*)p; p += (size_t)NG * NG * 2;     // 11.8 MB
    short* Grm  = (short*)p; p += (size_t)NG * NG * 2;     // 11.8 MB
    float* XD   = (float*)p; p += (size_t)MR * NG * 4;     // 19.9 MB
    short* Ya   = (short*)p; p += (size_t)MR * NG * 2;     // 10 MB
    short* Yb   = (short*)p; p += (size_t)MR * NG * 2;     // 10 MB
    short* Zp   = (short*)p; p += (size_t)MR * NG * 2;     // 10 MB

    // ---- prep ----
    k_makeD<<<(NP1 * NG + 255) / 256, 256, 0, stream>>>(D, Dp);
    k_makeDt<<<dim3(NG / 32, KP / 32), 256, 0, stream>>>(D, Dthi, Dtlo);
    k_makeX<<<(MR * KP + 255) / 256, 256, 0, stream>>>(x, Xhi, Xlo);

    // ---- G = D^T D (split, high precision) -> Gp packed + Grm row-major ----
    mfma_gemm<4, true><<<dim3(NG / 128, NG / 64), 256, 0, stream>>>(
        Dthi, Dtlo, KP, Dthi, Dtlo, KP, KP, 0,
        nullptr, nullptr, 0.0f, nullptr, nullptr, Gp, Grm, nullptr);

    // ---- XD = x @ D (split) -> fp32, stride NG ----
    mfma_gemm<3, true><<<dim3(608), 256, 0, stream>>>(
        Xhi, Xlo, KP, Dthi, Dtlo, KP, KP, 1,
        nullptr, nullptr, 0.0f, nullptr, nullptr, nullptr, nullptr, XD);

    // ---- power iteration on Grm ----
    k_init<<<1, 256, 0, stream>>>(w0, w1, part);
    for (int j = 0; j < 20; j++) {
        const float* win = (j & 1) ? w1 : w0;
        float* wout = (j & 1) ? w0 : w1;
        k_gmv<<<PPI, 1024, 0, stream>>>(Grm, win, part + j * PPI, wout,
                                        part + (j + 1) * PPI);
    }
    k_fin<<<1, 64, 0, stream>>>(part + 20 * PPI, scal);

    // ---- FISTA iter 0 (elementwise): z1 = soft(XD/L), y1 = z1 ----
    k_fista0<<<(MR * NG / 8 + 255) / 256, 256, 0, stream>>>(XD, scal, Zp, Ya);

    // ---- FISTA iters 1..15: z = soft(y - (yG - xD)/L); y ping-pong ----
    float t = 1.6180339887f;   // t after iter 0
    for (int i = 1; i < 16; i++) {
        float tn = 0.5f * (1.0f + sqrtf(1.0f + 4.0f * t * t));
        float mom = (t - 1.0f) / tn;
        t = tn;
        short* Yc = (i & 1) ? Ya : Yb;
        short* Yn = (i & 1) ? Yb : Ya;
        mfma_gemm<2, false><<<dim3(608), 256, 0, stream>>>(
            Yc, nullptr, NG, Gp, nullptr, NG, NG, 1,
            XD, scal, mom, Yn, Zp, nullptr, nullptr, nullptr);
    }

    // ---- final recon = z @ D^T -> out ----
    mfma_gemm<0, false><<<dim3(320), 256, 0, stream>>>(
        Zp, nullptr, NG, Dp, nullptr, NG, NG, 1,
        nullptr, nullptr, 0.0f, nullptr, nullptr, nullptr, nullptr, out);
}

// Round 7
// 882.278 us; speedup vs baseline: 12.4564x; 1.0660x over previous
//
#include <hip/hip_runtime.h>
#include <hip/hip_bf16.h>
#include <cmath>

// ---------------------------------------------------------------------------
// Sizes
// ---------------------------------------------------------------------------
#define DS 1200     // signal dim
#define DD 2400     // dict dim
#define MR 2048     // rows (B*N)
#define KP 1216     // padded signal dim (38*32)
#define NP1 1280    // padded signal dim for recon B panel (10*128)
#define NG 2432     // padded dict dim (19*128 = 38*64)
#define PPI 150     // norm partials per power iteration

typedef __attribute__((ext_vector_type(8))) short s16x8;
typedef __attribute__((ext_vector_type(4))) float f32x4;

__device__ __forceinline__ float s2f(short s) {
    union { unsigned u; float f; } c;
    c.u = ((unsigned)(unsigned short)s) << 16;
    return c.f;
}
__device__ __forceinline__ short f2s(float f) {
    __hip_bfloat16 h = __float2bfloat16(f);
    return *reinterpret_cast<short*>(&h);
}

// Packed layout: 128-row bands; within a band, 8-col k-subtiles of 1024 elems:
//   poff(m,k,C) = (m&~127)*C + (k>>3)*1024 + (m&127)*8 + (k&7)

// ---------------------------------------------------------------------------
// JAX threefry2x32 + XLA f32 erfinv (reproduce jax.random.normal(key(42)))
// ---------------------------------------------------------------------------
__device__ __forceinline__ unsigned rotl32(unsigned x, int d) {
    return (x << d) | (x >> (32 - d));
}

__device__ void threefry2x32(unsigned k0, unsigned k1, unsigned x0, unsigned x1,
                             unsigned* o0, unsigned* o1) {
    unsigned ks0 = k0, ks1 = k1, ks2 = k0 ^ k1 ^ 0x1BD11BDAu;
    const int rotA[4] = {13, 15, 26, 6};
    const int rotB[4] = {17, 29, 16, 24};
    x0 += ks0; x1 += ks1;
    #pragma unroll
    for (int r = 0; r < 4; r++) { x0 += x1; x1 = rotl32(x1, rotA[r]); x1 ^= x0; }
    x0 += ks1; x1 += ks2 + 1u;
    #pragma unroll
    for (int r = 0; r < 4; r++) { x0 += x1; x1 = rotl32(x1, rotB[r]); x1 ^= x0; }
    x0 += ks2; x1 += ks0 + 2u;
    #pragma unroll
    for (int r = 0; r < 4; r++) { x0 += x1; x1 = rotl32(x1, rotA[r]); x1 ^= x0; }
    x0 += ks0; x1 += ks1 + 3u;
    #pragma unroll
    for (int r = 0; r < 4; r++) { x0 += x1; x1 = rotl32(x1, rotB[r]); x1 ^= x0; }
    x0 += ks1; x1 += ks2 + 4u;
    #pragma unroll
    for (int r = 0; r < 4; r++) { x0 += x1; x1 = rotl32(x1, rotA[r]); x1 ^= x0; }
    x0 += ks2; x1 += ks0 + 5u;
    *o0 = x0; *o1 = x1;
}

__device__ float erfinv_f32(float x) {
    float w = -logf((1.0f - x) * (1.0f + x));
    float p;
    if (w < 5.0f) {
        w -= 2.5f;
        p = 2.81022636e-08f;
        p = fmaf(p, w, 3.43273939e-07f);
        p = fmaf(p, w, -3.5233877e-06f);
        p = fmaf(p, w, -4.39150654e-06f);
        p = fmaf(p, w, 0.00021858087f);
        p = fmaf(p, w, -0.00125372503f);
        p = fmaf(p, w, -0.00417768164f);
        p = fmaf(p, w, 0.246640727f);
        p = fmaf(p, w, 1.50140941f);
    } else {
        w = sqrtf(w) - 3.0f;
        p = -0.000200214257f;
        p = fmaf(p, w, 0.000100950558f);
        p = fmaf(p, w, 0.00134934322f);
        p = fmaf(p, w, -0.00367342844f);
        p = fmaf(p, w, 0.00573950773f);
        p = fmaf(p, w, -0.0076224613f);
        p = fmaf(p, w, 0.00943887047f);
        p = fmaf(p, w, 1.00167406f);
        p = fmaf(p, w, 2.83297682f);
    }
    return p * x;
}

__device__ float bits_to_normal(unsigned bits) {
    unsigned fb = (bits >> 9) | 0x3F800000u;
    float u01 = __uint_as_float(fb) - 1.0f;
    const float lo = -0.99999994f;
    float u = u01 * 2.0f + lo;
    u = fmaxf(lo, u);
    return 1.41421356237f * erfinv_f32(u);
}

// ---------------------------------------------------------------------------
// Power iteration pieces
// ---------------------------------------------------------------------------
__global__ void k_init(float* __restrict__ w0, float* __restrict__ w1,
                       float* __restrict__ part) {
    int tid = threadIdx.x;
    for (int i = tid; i < 21 * PPI; i += 256) part[i] = 0.0f;
    if (tid < 32) {
        w0[2400 + tid] = 0.0f;
        w1[2400 + tid] = 0.0f;
    }
    __shared__ float red[256];
    float local2 = 0.0f;
    for (int p = tid; p < DS; p += 256) {
        unsigned r0, r1;
        threefry2x32(0u, 42u, (unsigned)p, (unsigned)(DS + p), &r0, &r1);
        float n0 = bits_to_normal(r0);
        float n1 = bits_to_normal(r1);
        w0[p] = n0;
        w0[DS + p] = n1;
        local2 += n0 * n0 + n1 * n1;
    }
    red[tid] = local2;
    __syncthreads();
    for (int s = 128; s > 0; s >>= 1) {
        if (tid < s) red[tid] += red[tid + s];
        __syncthreads();
    }
    if (tid == 0) part[0] = red[0];
}

__global__ __launch_bounds__(1024) void k_gmv(const short* __restrict__ Grm,
                                              const float* __restrict__ win,
                                              const float* __restrict__ partin,
                                              float* __restrict__ wout,
                                              float* __restrict__ partout) {
    float s2 = 0.0f;
    for (int i = 0; i < PPI; i++) s2 += partin[i];
    float rn = 1.0f / sqrtf(s2);
    int wave = threadIdx.x >> 6, lane = threadIdx.x & 63;
    int row = blockIdx.x * 16 + wave;       // 150 * 16 = 2400 rows
    const s16x8* gh = (const s16x8*)(Grm + (size_t)row * NG);
    const float4* w4 = (const float4*)win;
    float acc = 0.0f;
    #pragma unroll
    for (int i = 0; i < 5; i++) {
        int c = lane + i * 64;              // 304 chunks
        if (c < 304) {
            s16x8 h = gh[c];
            float4 wa = w4[c * 2], wb = w4[c * 2 + 1];
            acc += s2f(h[0]) * wa.x + s2f(h[1]) * wa.y;
            acc += s2f(h[2]) * wa.z + s2f(h[3]) * wa.w;
            acc += s2f(h[4]) * wb.x + s2f(h[5]) * wb.y;
            acc += s2f(h[6]) * wb.z + s2f(h[7]) * wb.w;
        }
    }
    #pragma unroll
    for (int off = 32; off > 0; off >>= 1) acc += __shfl_xor(acc, off, 64);
    __shared__ float red[16];
    if (lane == 0) {
        float val = acc * rn;
        wout[row] = val;
        red[wave] = val * val;
    }
    __syncthreads();
    if (threadIdx.x == 0) {
        float s = 0.0f;
        #pragma unroll
        for (int i = 0; i < 16; i++) s += red[i];
        partout[blockIdx.x] = s;
    }
}

__global__ void k_fin(const float* __restrict__ part20, float* __restrict__ scal) {
    if (threadIdx.x == 0) {
        float s = 0.0f;
        for (int i = 0; i < PPI; i++) s += part20[i];
        float L = sqrtf(s);
        scal[0] = L;
        scal[1] = 1.0f / L;
        scal[2] = 0.1f / L;
    }
}

// ---------------------------------------------------------------------------
// Prep kernels (write packed layouts)
// ---------------------------------------------------------------------------
__global__ void k_makeD(const float* __restrict__ D, short* __restrict__ Dp) {
    int p = blockIdx.x * 256 + threadIdx.x;     // NP1*NG
    if (p >= NP1 * NG) return;
    int tile = p >> 10, win = p & 1023;
    int row = win >> 3, e = win & 7;
    int mt = tile / (NG >> 3), ct = tile % (NG >> 3);
    int d = mt * 128 + row, n = ct * 8 + e;
    float v = (d < DS && n < DD) ? D[(size_t)d * DD + n] : 0.0f;
    Dp[p] = f2s(v);
}

__global__ void k_makeX(const float* __restrict__ x,
                        short* __restrict__ Xhi, short* __restrict__ Xlo) {
    int p = blockIdx.x * 256 + threadIdx.x;     // MR*KP
    if (p >= MR * KP) return;
    int tile = p >> 10, win = p & 1023;
    int row = win >> 3, e = win & 7;
    int mt = tile / (KP >> 3), ct = tile % (KP >> 3);
    int m = mt * 128 + row, k = ct * 8 + e;
    float v = (k < DS) ? x[(size_t)m * DS + k] : 0.0f;
    short h = f2s(v);
    Xhi[p] = h;
    Xlo[p] = f2s(v - s2f(h));
}

__global__ void k_makeDt(const float* __restrict__ D,
                         short* __restrict__ Dthi, short* __restrict__ Dtlo) {
    __shared__ float t[32][33];
    int bc = blockIdx.x * 32;   // dict base
    int bk = blockIdx.y * 32;   // signal base
    int tx = threadIdx.x & 31, ty = threadIdx.x >> 5;
    for (int i = ty; i < 32; i += 8) {
        int k = bk + i, c = bc + tx;
        t[i][tx] = (k < DS && c < DD) ? D[(size_t)k * DD + c] : 0.0f;
    }
    __syncthreads();
    for (int i = ty; i < 32; i += 8) {
        int c = bc + i, k = bk + tx;
        float v = t[tx][i];
        short h = f2s(v);
        size_t po = ((size_t)(c >> 7) * (KP >> 3) + (k >> 3)) * 1024 +
                    ((c & 127) << 3) + (k & 7);
        Dthi[po] = h;
        Dtlo[po] = f2s(v - s2f(h));
    }
}

// W = I - G/L, bf16 packed layout, from fp32 row-major G.
__global__ void k_makeW(const float* __restrict__ Gf, const float* __restrict__ scal,
                        short* __restrict__ Wp) {
    int i = blockIdx.x * 256 + threadIdx.x;      // over NG*NG/8
    if (i >= NG * NG / 8) return;
    float invL = scal[1];
    int e0 = i * 8;
    int band = e0 / (128 * NG);
    int rem = e0 - band * (128 * NG);
    int tile = rem >> 10;
    int row = (rem & 1023) >> 3;
    int m = band * 128 + row;       // W row (output index n)
    int k0 = tile * 8;              // W col (contraction index k)
    const float4* gp = (const float4*)(Gf + (size_t)m * NG + k0);
    float4 g0 = gp[0], g1 = gp[1];
    float gv[8] = {g0.x, g0.y, g0.z, g0.w, g1.x, g1.y, g1.z, g1.w};
    s16x8 wv;
    #pragma unroll
    for (int e = 0; e < 8; e++) {
        float wf = ((k0 + e == m) ? 1.0f : 0.0f) - gv[e] * invL;
        wv[e] = f2s(wf);
    }
    ((s16x8*)Wp)[i] = wv;
}

// FISTA iteration 0 (y0=0): z1 = soft(XD/L, thr); y1 = z1 (mom=0).
__global__ void k_fista0(const float* __restrict__ XD, const float* __restrict__ scal,
                         short* __restrict__ Z, short* __restrict__ Y) {
    int i = blockIdx.x * 256 + threadIdx.x;      // over MR*NG/8
    if (i >= MR * NG / 8) return;
    float invL = scal[1], thr = scal[2];
    int e0 = i * 8;
    int band = e0 / (128 * NG);
    int rem = e0 - band * (128 * NG);
    int tile = rem >> 10;
    int row = (rem & 1023) >> 3;
    int m = band * 128 + row;
    int n = tile * 8;
    const float4* xp = (const float4*)(XD + (size_t)m * NG + n);
    float4 v0 = xp[0], v1 = xp[1];
    float vs[8] = {v0.x, v0.y, v0.z, v0.w, v1.x, v1.y, v1.z, v1.w};
    s16x8 zs;
    #pragma unroll
    for (int k = 0; k < 8; k++) {
        float gs = vs[k] * invL;
        float az = fabsf(gs) - thr;
        float zn = (az > 0.0f) ? copysignf(az, gs) : 0.0f;
        zs[k] = f2s(zn);
    }
    ((s16x8*)Z)[i] = zs;
    ((s16x8*)Y)[i] = zs;
}

// ---------------------------------------------------------------------------
// MFMA GEMM on packed operands. Tile 64(M) x 128(N), 4 waves (32x64 each).
// SPLIT: BK=32, 3-MFMA hi/lo split.  non-SPLIT: BK=64, single bf16.
//   out[m][n] = sum_k A[m][k] * B[n][k]
// EPI 0: Out[m*DS+n] = acc (n<DS)                  (final recon)
// EPI 2: FISTA (W-form): gs=acc+XD*invL; z=soft(gs); ynext=z+mom(z-zold)
// EPI 3: Out[m*NG+n] = acc fp32                    (XD precompute)
// EPI 4: Grm[m*NG+n]=bf16(acc); Out[m*NG+n]=acc    (G precompute: bf16 + fp32)
// ---------------------------------------------------------------------------
__device__ __forceinline__ void gload16(const void* g, void* l) {
    __builtin_amdgcn_global_load_lds(
        (const __attribute__((address_space(1))) unsigned int*)g,
        (__attribute__((address_space(3))) unsigned int*)l, 16, 0, 0);
}

template <int EPI, bool SPLIT>
__global__ __launch_bounds__(256, 4) void mfma_gemm(
    const short* __restrict__ Ah, const short* __restrict__ Al, int CA,
    const short* __restrict__ Bh, const short* __restrict__ Bl, int CB,
    int K, int swz,
    const float* __restrict__ XDc, const float* __restrict__ scal, float mom,
    short* __restrict__ Ynew, short* __restrict__ Zst,
    short* __restrict__ Grm,
    float* __restrict__ Out) {
    // LDS regions (shorts): A at 0 (+Al at 2048 if SPLIT); B at 4096 (+Bl at 8192)
    constexpr int ALO = 2048;
    constexpr int BHO = 4096;
    constexpr int BLO = 8192;
    constexpr int BUF = 12288;                // 24 KB per buffer, both modes
    __shared__ __align__(16) short lds[2 * BUF];

    const int tid = threadIdx.x;
    const int w = tid >> 6, lane = tid & 63;
    const int fm = lane & 15, kg = lane >> 4;
    const int wr = w >> 1, wc = w & 1;        // wave -> 32x64 quadrant

    int bx, by;
    if (swz) {
        int q = gridDim.x >> 3;               // grid divisible by 8
        int s = (blockIdx.x & 7) * q + (blockIdx.x >> 3);
        by = s & 31; bx = s >> 5;             // 32 M-blocks (M=2048)
    } else { bx = blockIdx.x; by = blockIdx.y; }
    const int m0 = by * 64, n0 = bx * 128;

    f32x4 acc[2][4];
    #pragma unroll
    for (int g = 0; g < 2; ++g)
        #pragma unroll
        for (int h = 0; h < 4; ++h) acc[g][h] = f32x4{0.f, 0.f, 0.f, 0.f};

    float invL = 0.0f, thr = 0.0f;
    if (EPI == 2) { invL = scal[1]; thr = scal[2]; }

    const int half = (m0 >> 6) & 1;
    const int nk = K / (SPLIT ? 32 : 64);

    // staging source bases (per-lane global, wave-uniform LDS dest)
    const size_t AbS = (size_t)(m0 & ~127) * CA + w * 1024 + half * 512 + lane * 8;
    const size_t BbS = (size_t)n0 * CB + w * 512 + lane * 8;
    const size_t AbN = (size_t)(m0 & ~127) * CA + half * 512 + lane * 8;
    const size_t BbN = (size_t)n0 * CB + lane * 8;

    auto STAGE = [&](int t, int cur) {
        short* bp = &lds[cur * BUF];
        if constexpr (SPLIT) {
            const size_t kk = (size_t)t << 12;        // 32*128 elems
            gload16(Ah + AbS + kk, bp + w * 512);
            gload16(Bh + BbS + kk, bp + BHO + w * 512);
            gload16(Bh + BbS + kk + 2048, bp + BHO + 2048 + w * 512);
            gload16(Al + AbS + kk, bp + ALO + w * 512);
            gload16(Bl + BbS + kk, bp + BLO + w * 512);
            gload16(Bl + BbS + kk + 2048, bp + BLO + 2048 + w * 512);
        } else {
            const size_t kk = (size_t)t << 13;        // 64*128 elems
            const int cs0 = 2 * w, cs1 = 2 * w + 1;
            gload16(Ah + AbN + kk + cs0 * 1024, bp + cs0 * 512);
            gload16(Ah + AbN + kk + cs1 * 1024, bp + cs1 * 512);
            gload16(Bh + BbN + kk + cs0 * 1024,       bp + BHO + cs0 * 1024);
            gload16(Bh + BbN + kk + cs0 * 1024 + 512, bp + BHO + cs0 * 1024 + 512);
            gload16(Bh + BbN + kk + cs1 * 1024,       bp + BHO + cs1 * 1024);
            gload16(Bh + BbN + kk + cs1 * 1024 + 512, bp + BHO + cs1 * 1024 + 512);
        }
    };

    STAGE(0, 0);

    for (int t = 0; t < nk; ++t) {
        __syncthreads();                      // drains staged loads for tile t
        if (t + 1 < nk) STAGE(t + 1, (t + 1) & 1);
        const short* bs = &lds[(t & 1) * BUF];

        #pragma unroll
        for (int ks = 0; ks < (SPLIT ? 1 : 2); ++ks) {
            const int c = ks * 4 + kg;
            s16x8 a[2], b[4];
            #pragma unroll
            for (int g = 0; g < 2; ++g)
                a[g] = *(const s16x8*)&bs[c * 512 + (wr * 32 + g * 16 + fm) * 8];
            #pragma unroll
            for (int h = 0; h < 4; ++h)
                b[h] = *(const s16x8*)&bs[BHO + c * 1024 + (wc * 64 + h * 16 + fm) * 8];
            if constexpr (SPLIT) {
                s16x8 a2[2], b2[4];
                #pragma unroll
                for (int g = 0; g < 2; ++g)
                    a2[g] = *(const s16x8*)&bs[ALO + c * 512 + (wr * 32 + g * 16 + fm) * 8];
                #pragma unroll
                for (int h = 0; h < 4; ++h)
                    b2[h] = *(const s16x8*)&bs[BLO + c * 1024 + (wc * 64 + h * 16 + fm) * 8];
                #pragma unroll
                for (int g = 0; g < 2; ++g)
                    #pragma unroll
                    for (int h = 0; h < 4; ++h) {
                        acc[g][h] = __builtin_amdgcn_mfma_f32_16x16x32_bf16(a[g], b[h], acc[g][h], 0, 0, 0);
                        acc[g][h] = __builtin_amdgcn_mfma_f32_16x16x32_bf16(a[g], b2[h], acc[g][h], 0, 0, 0);
                        acc[g][h] = __builtin_amdgcn_mfma_f32_16x16x32_bf16(a2[g], b[h], acc[g][h], 0, 0, 0);
                    }
            } else {
                #pragma unroll
                for (int g = 0; g < 2; ++g)
                    #pragma unroll
                    for (int h = 0; h < 4; ++h)
                        acc[g][h] = __builtin_amdgcn_mfma_f32_16x16x32_bf16(a[g], b[h], acc[g][h], 0, 0, 0);
            }
        }
    }

    // epilogue: frag (row = kg*4+j, col = fm)
    #pragma unroll
    for (int g = 0; g < 2; ++g) {
        #pragma unroll
        for (int h = 0; h < 4; ++h) {
            #pragma unroll
            for (int j = 0; j < 4; ++j) {
                int m = m0 + wr * 32 + g * 16 + kg * 4 + j;
                int n = n0 + wc * 64 + h * 16 + fm;
                float v = acc[g][h][j];
                if (EPI == 0) {
                    if (n < DS) Out[(size_t)m * DS + n] = v;
                } else if (EPI == 2) {
                    size_t o = (size_t)m * NG + n;
                    size_t pz = (size_t)(m & ~127) * NG + ((n >> 3) << 10) +
                                ((m & 127) << 3) + (n & 7);
                    float gs = fmaf(XDc[o], invL, v);
                    float az = fabsf(gs) - thr;
                    float zn = (az > 0.0f) ? copysignf(az, gs) : 0.0f;
                    float zold = s2f(Zst[pz]);
                    float yn = zn + mom * (zn - zold);
                    Zst[pz] = f2s(zn);
                    Ynew[pz] = f2s(yn);
                } else if (EPI == 3) {
                    Out[(size_t)m * NG + n] = v;
                } else {  // EPI == 4: G -> bf16 row-major + fp32 row-major
                    size_t o = (size_t)m * NG + n;
                    Grm[o] = f2s(v);
                    Out[o] = v;
                }
            }
        }
    }
}

// ---------------------------------------------------------------------------
// Launch
// ---------------------------------------------------------------------------
extern "C" void kernel_launch(void* const* d_in, const int* in_sizes, int n_in,
                              void* d_out, int out_size, void* d_ws, size_t ws_size,
                              hipStream_t stream) {
    const float* x = (const float*)d_in[0];   // (2048, 1200)
    const float* D = (const float*)d_in[1];   // (1200, 2400)
    float* out = (float*)d_out;               // (2048, 1200)

    char* wsb = (char*)d_ws;
    float* w0 = (float*)wsb;                  // 2432
    float* w1 = w0 + 2432;
    float* part = w1 + 2432;                  // 21*150
    float* scal = part + 3200;                // 3

    char* p = wsb + 65536;
    short* Dp   = (short*)p; p += (size_t)NP1 * NG * 2;    // 6.2 MB
    short* Dthi = (short*)p; p += (size_t)NG * KP * 2;     // 5.9 MB
    short* Dtlo = (short*)p; p += (size_t)NG * KP * 2;
    short* Xhi  = (short*)p; p += (size_t)MR * KP * 2;     // 5.0 MB
    short* Xlo  = (short*)p; p += (size_t)MR * KP * 2;
    short* Wp   = (short*)p; p += (size_t)NG * NG * 2;     // 11.8 MB (packed W)
    short* Grm  = (short*)p; p += (size_t)NG * NG * 2;     // 11.8 MB (bf16 G, rm)
    float* XD   = (float*)p; p += (size_t)MR * NG * 4;     // 19.9 MB
    short* Ya   = (short*)p; p += (size_t)MR * NG * 2;     // 10 MB
    short* Yb   = (short*)p; p += (size_t)MR * NG * 2;     // 10 MB
    short* Zp   = (short*)p; p += (size_t)MR * NG * 2;     // 10 MB
    float* Gf   = (float*)Ya;   // fp32 G (23.6 MB) overlays Ya/Yb/Zp, dead
                                // before k_fista0 writes them

    // ---- prep ----
    k_makeD<<<(NP1 * NG + 255) / 256, 256, 0, stream>>>(D, Dp);
    k_makeDt<<<dim3(NG / 32, KP / 32), 256, 0, stream>>>(D, Dthi, Dtlo);
    k_makeX<<<(MR * KP + 255) / 256, 256, 0, stream>>>(x, Xhi, Xlo);

    // ---- G = D^T D (split, high precision) -> Grm bf16 + Gf fp32 ----
    mfma_gemm<4, true><<<dim3(NG / 128, NG / 64), 256, 0, stream>>>(
        Dthi, Dtlo, KP, Dthi, Dtlo, KP, KP, 0,
        nullptr, nullptr, 0.0f, nullptr, nullptr, Grm, Gf);

    // ---- power iteration on Grm ----
    k_init<<<1, 256, 0, stream>>>(w0, w1, part);
    for (int j = 0; j < 20; j++) {
        const float* win = (j & 1) ? w1 : w0;
        float* wout = (j & 1) ? w0 : w1;
        k_gmv<<<PPI, 1024, 0, stream>>>(Grm, win, part + j * PPI, wout,
                                        part + (j + 1) * PPI);
    }
    k_fin<<<1, 64, 0, stream>>>(part + 20 * PPI, scal);

    // ---- W = I - G/L (bf16, packed) ----
    k_makeW<<<(NG * NG / 8 + 255) / 256, 256, 0, stream>>>(Gf, scal, Wp);

    // ---- XD = x @ D (split) -> fp32, stride NG ----
    mfma_gemm<3, true><<<dim3(608), 256, 0, stream>>>(
        Xhi, Xlo, KP, Dthi, Dtlo, KP, KP, 1,
        nullptr, nullptr, 0.0f, nullptr, nullptr, nullptr, XD);

    // ---- FISTA iter 0 (elementwise): z1 = soft(XD/L), y1 = z1 ----
    // (overwrites the Gf overlay -- Gf is dead after k_makeW)
    k_fista0<<<(MR * NG / 8 + 255) / 256, 256, 0, stream>>>(XD, scal, Zp, Ya);

    // ---- FISTA iters 1..15: z = soft(yW + xD/L); y ping-pong ----
    float t = 1.6180339887f;   // t after iter 0
    for (int i = 1; i < 16; i++) {
        float tn = 0.5f * (1.0f + sqrtf(1.0f + 4.0f * t * t));
        float mom = (t - 1.0f) / tn;
        t = tn;
        short* Yc = (i & 1) ? Ya : Yb;
        short* Yn = (i & 1) ? Yb : Ya;
        mfma_gemm<2, false><<<dim3(608), 256, 0, stream>>>(
            Yc, nullptr, NG, Wp, nullptr, NG, NG, 1,
            XD, scal, mom, Yn, Zp, nullptr, nullptr);
    }

    // ---- final recon = z @ D^T -> out ----
    mfma_gemm<0, false><<<dim3(320), 256, 0, stream>>>(
        Zp, nullptr, NG, Dp, nullptr, NG, NG, 1,
        nullptr, nullptr, 0.0f, nullptr, nullptr, nullptr, out);
}